// Round 1
// baseline (1127.955 us; speedup 1.0000x reference)
//
#include <hip/hip_runtime.h>
#include <hip/hip_bf16.h>

// Problem constants
constexpr int B_ = 16;
constexpr int S_ = 2048;
constexpr int D_ = 1024;
constexpr long long BSD = (long long)B_ * S_ * D_;   // 33,554,432 elements

typedef unsigned short u16;
typedef __bf16 bf16x8 __attribute__((ext_vector_type(8)));
typedef float    f32x4 __attribute__((ext_vector_type(4)));
typedef unsigned short usx8 __attribute__((ext_vector_type(8)));
typedef unsigned short usx4 __attribute__((ext_vector_type(4)));

__device__ inline u16 f2b(float f) {            // f32 -> bf16 RNE
  unsigned u = __float_as_uint(f);
  u = (u + 0x7fffu + ((u >> 16) & 1u)) >> 16;
  return (u16)u;
}
__device__ inline float b2f(u16 v) { return __uint_as_float(((unsigned)v) << 16); }

// ---------------- bias pack: [bq|bk|bv] -> contiguous ----------------
__global__ void k_pack_bias(const float* __restrict__ bq, const float* __restrict__ bk,
                            const float* __restrict__ bv, float* __restrict__ dst) {
  int t = blockIdx.x * 256 + threadIdx.x;          // 3072 threads
  if (t < 1024) dst[t] = bq[t];
  else if (t < 2048) dst[t] = bk[t - 1024];
  else dst[t] = bv[t - 2048];
}

// ---------------- transpose+convert W[k][n] (f32) -> Wt[n][k] (bf16) ----------------
__global__ __launch_bounds__(256) void k_transpose_cvt(const float* __restrict__ W,
                                                       u16* __restrict__ Wt) {
  __shared__ float tile[32][33];
  const int n0 = blockIdx.x * 32, k0 = blockIdx.y * 32;
  const int tx = threadIdx.x & 31, ty = threadIdx.x >> 5;   // ty 0..7
  for (int r = ty; r < 32; r += 8)
    tile[r][tx] = W[(size_t)(k0 + r) * D_ + n0 + tx];
  __syncthreads();
  for (int r = ty; r < 32; r += 8)
    Wt[(size_t)(n0 + r) * D_ + k0 + tx] = f2b(tile[tx][r]);
}

// ---------------- GEMM (B-transposed input): C[m,n] = scale * sum_k A[m,k]*Bt[n,k] + bias[n]
// 128x128 tile, BK=64, 256 threads (4 waves, each 64x64 = 4x4 MFMA 16x16x32 frags)
template <bool AF32, bool BIAS>
__global__ __launch_bounds__(256) void k_gemm_bt(
    const void* __restrict__ Av, const u16* __restrict__ Bt,
    const float* __restrict__ bias, u16* __restrict__ C,
    int M, int N, int K, float scale,
    long long sA_z, long long sB_z, long long sC_z, int biasStride) {
  constexpr int BM = 128, BN = 128, BK = 64;
  __shared__ u16 sA[BM * BK];
  __shared__ u16 sB[BN * BK];
  const int tid = threadIdx.x;
  const int lane = tid & 63, wave = tid >> 6;
  const int z = blockIdx.z;
  const u16* A16 = (const u16*)Av + (AF32 ? 0 : z * sA_z);
  const float* A32 = (const float*)Av + (AF32 ? z * sA_z : 0);
  const u16* Bz = Bt + z * sB_z;
  u16* Cz = C + z * sC_z;
  const int m0 = blockIdx.y * BM, n0 = blockIdx.x * BN;
  const int wm = (wave >> 1) * 64, wn = (wave & 1) * 64;
  const int sr = tid >> 3;          // 0..31 (row within 32-row chunk)
  const int scl = (tid & 7) * 8;    // col element (0..56 step 8)

  f32x4 acc[4][4] = {};

  for (int kt = 0; kt < K; kt += BK) {
    usx8 ra[4], rb[4];
#pragma unroll
    for (int cch = 0; cch < 4; cch++) {
      const int row = cch * 32 + sr;
      if (AF32) {
        const float* p = A32 + (size_t)(m0 + row) * K + kt + scl;
        f32x4 lo = *(const f32x4*)p;
        f32x4 hi = *(const f32x4*)(p + 4);
        usx8 t;
        t[0] = f2b(lo[0]); t[1] = f2b(lo[1]); t[2] = f2b(lo[2]); t[3] = f2b(lo[3]);
        t[4] = f2b(hi[0]); t[5] = f2b(hi[1]); t[6] = f2b(hi[2]); t[7] = f2b(hi[3]);
        ra[cch] = t;
      } else {
        ra[cch] = *(const usx8*)(A16 + (size_t)(m0 + row) * K + kt + scl);
      }
      rb[cch] = *(const usx8*)(Bz + (size_t)(n0 + row) * K + kt + scl);
    }
    __syncthreads();
#pragma unroll
    for (int cch = 0; cch < 4; cch++) {
      *(usx8*)(sA + (cch * 32 + sr) * BK + scl) = ra[cch];
      *(usx8*)(sB + (cch * 32 + sr) * BK + scl) = rb[cch];
    }
    __syncthreads();
#pragma unroll
    for (int kk = 0; kk < BK; kk += 32) {
      bf16x8 af[4], bfr[4];
#pragma unroll
      for (int i = 0; i < 4; i++)
        af[i] = *(const bf16x8*)(sA + (wm + i * 16 + (lane & 15)) * BK + kk + (lane >> 4) * 8);
#pragma unroll
      for (int j = 0; j < 4; j++)
        bfr[j] = *(const bf16x8*)(sB + (wn + j * 16 + (lane & 15)) * BK + kk + (lane >> 4) * 8);
#pragma unroll
      for (int i = 0; i < 4; i++)
#pragma unroll
        for (int j = 0; j < 4; j++)
          acc[i][j] = __builtin_amdgcn_mfma_f32_16x16x32_bf16(af[i], bfr[j], acc[i][j], 0, 0, 0);
    }
  }
  // epilogue: C/D layout col = lane&15, row = (lane>>4)*4 + r
#pragma unroll
  for (int i = 0; i < 4; i++) {
    const int r0 = m0 + wm + i * 16 + ((lane >> 4) << 2);
#pragma unroll
    for (int j = 0; j < 4; j++) {
      const int col = n0 + wn + j * 16 + (lane & 15);
      const float badd = BIAS ? bias[z * biasStride + col] : 0.0f;
#pragma unroll
      for (int r = 0; r < 4; r++) {
        float v = acc[i][j][r] * scale + badd;
        Cz[(size_t)(r0 + r) * N + col] = f2b(v);
      }
    }
  }
}

// ---------------- softmax rows + column-sum: c[b,k] = (1/S) * sum_q softmax(scores[b,q,:])[k]
__global__ __launch_bounds__(256) void k_softmax_colsum(
    const u16* __restrict__ scores, const int* __restrict__ mask, float* __restrict__ c) {
  __shared__ float am[S_];        // additive mask
  __shared__ float colsum[S_];
  const int b = blockIdx.y;
  const int r0 = blockIdx.x * 32;
  const int tid = threadIdx.x, lane = tid & 63, wave = tid >> 6;
  for (int k = tid; k < S_; k += 256) {
    am[k] = (mask[b * S_ + k] != 0) ? 0.0f : -__builtin_huge_valf();
    colsum[k] = 0.0f;
  }
  __syncthreads();
  const u16* srow_base = scores + (size_t)b * S_ * S_;
  for (int rr = 0; rr < 8; rr++) {
    const int r = r0 + wave * 8 + rr;
    const u16* srow = srow_base + (size_t)r * S_;
    float s[32];
    float m = -__builtin_huge_valf();
#pragma unroll
    for (int i = 0; i < 32; i++) {
      const int k = lane + i * 64;
      float v = b2f(srow[k]) + am[k];
      s[i] = v;
      m = fmaxf(m, v);
    }
#pragma unroll
    for (int o = 1; o < 64; o <<= 1) m = fmaxf(m, __shfl_xor(m, o));
    float sum = 0.f;
#pragma unroll
    for (int i = 0; i < 32; i++) { s[i] = __expf(s[i] - m); sum += s[i]; }
#pragma unroll
    for (int o = 1; o < 64; o <<= 1) sum += __shfl_xor(sum, o);
    const float inv = 1.0f / (sum * (float)S_);
#pragma unroll
    for (int i = 0; i < 32; i++) atomicAdd(&colsum[lane + i * 64], s[i] * inv);
  }
  __syncthreads();
  for (int k = tid; k < S_; k += 256) atomicAdd(&c[b * S_ + k], colsum[k]);
}

// ---------------- pooled[b,d] = sum_k c[b,k] * V[b,k,d]
__global__ __launch_bounds__(256) void k_cv(const float* __restrict__ c,
                                            const u16* __restrict__ Vb,
                                            float* __restrict__ pooled) {
  const int b = blockIdx.y;
  const int k0 = blockIdx.x * 256;
  const int tid = threadIdx.x;
  f32x4 acc = {};
  const u16* vb = Vb + ((size_t)b * S_ + k0) * D_ + tid * 4;
  const float* cb = c + b * S_ + k0;
  for (int k = 0; k < 256; k++) {
    const float w = cb[k];
    usx4 v = *(const usx4*)(vb + (size_t)k * D_);
    acc[0] += w * b2f(v[0]);
    acc[1] += w * b2f(v[1]);
    acc[2] += w * b2f(v[2]);
    acc[3] += w * b2f(v[3]);
  }
#pragma unroll
  for (int q = 0; q < 4; q++) atomicAdd(&pooled[b * D_ + tid * 4 + q], acc[q]);
}

// ---------------- hpre = pooled @ W1 (accumulated via atomics)
__global__ __launch_bounds__(256) void k_mlp1(const float* __restrict__ pooled,
                                              const float* __restrict__ W1,
                                              float* __restrict__ hpre) {
  __shared__ float ps[16][256];
  const int tid = threadIdx.x;
  const int j = blockIdx.x * 256 + tid;
  const int i0 = blockIdx.y * 256;
  for (int x = tid; x < 16 * 256; x += 256) {
    const int bb = x >> 8, ii = x & 255;
    ps[bb][ii] = pooled[bb * D_ + i0 + ii];
  }
  __syncthreads();
  float acc[16] = {};
  for (int i = 0; i < 256; i++) {
    const float w = W1[(size_t)(i0 + i) * (4 * D_) + j];
#pragma unroll
    for (int bb = 0; bb < 16; bb++) acc[bb] += ps[bb][i] * w;
  }
#pragma unroll
  for (int bb = 0; bb < 16; bb++) atomicAdd(&hpre[bb * (4 * D_) + j], acc[bb]);
}

// ---------------- outpre = relu(hpre + b1) @ W2 (accumulated via atomics)
__global__ __launch_bounds__(256) void k_mlp2(const float* __restrict__ hpre,
                                              const float* __restrict__ b1,
                                              const float* __restrict__ W2,
                                              float* __restrict__ outpre) {
  __shared__ float hs[16][256];
  const int tid = threadIdx.x;
  const int n = blockIdx.x * 256 + tid;
  const int i0 = blockIdx.y * 256;
  for (int x = tid; x < 16 * 256; x += 256) {
    const int bb = x >> 8, ii = x & 255;
    hs[bb][ii] = fmaxf(hpre[bb * (4 * D_) + i0 + ii] + b1[i0 + ii], 0.0f);
  }
  __syncthreads();
  float acc[16] = {};
  for (int i = 0; i < 256; i++) {
    const float w = W2[(size_t)(i0 + i) * D_ + n];
#pragma unroll
    for (int bb = 0; bb < 16; bb++) acc[bb] += hs[bb][i] * w;
  }
#pragma unroll
  for (int bb = 0; bb < 16; bb++) atomicAdd(&outpre[bb * D_ + n], acc[bb]);
}

// ---------------- out = tanh(outpre + b2)
__global__ void k_finish(const float* __restrict__ outpre, const float* __restrict__ b2,
                         float* __restrict__ out) {
  const int x = blockIdx.x * 256 + threadIdx.x;   // 16384
  out[x] = tanhf(outpre[x] + b2[x & (D_ - 1)]);
}

extern "C" void kernel_launch(void* const* d_in, const int* in_sizes, int n_in,
                              void* d_out, int out_size, void* d_ws, size_t ws_size,
                              hipStream_t stream) {
  const float* X  = (const float*)d_in[0];
  const int* mask = (const int*)d_in[1];
  const float* Wq = (const float*)d_in[2];
  const float* bq = (const float*)d_in[3];
  const float* Wk = (const float*)d_in[4];
  const float* bk = (const float*)d_in[5];
  const float* Wv = (const float*)d_in[6];
  const float* bv = (const float*)d_in[7];
  const float* W1 = (const float*)d_in[8];
  const float* b1 = (const float*)d_in[9];
  const float* W2 = (const float*)d_in[10];
  const float* b2 = (const float*)d_in[11];
  float* out = (float*)d_out;

  char* ws = (char*)d_ws;
  size_t off = 0;
  auto alloc = [&](size_t bytes) -> void* {
    void* p = ws + off;
    off += (bytes + 255) & ~(size_t)255;
    return p;
  };
  u16* QKVb = (u16*)alloc(3 * BSD * sizeof(u16));                 // 192 MB: Q|K|V bf16
  u16* Qb = QKVb;
  u16* Kb = QKVb + BSD;
  u16* Vb = QKVb + 2 * BSD;
  u16* Sc = (u16*)alloc((size_t)B_ * S_ * S_ * sizeof(u16));      // 128 MB scores bf16
  u16* Wt = (u16*)alloc((size_t)3 * D_ * D_ * sizeof(u16));       // 6 MB
  float* biasQKV = (float*)alloc(3 * D_ * sizeof(float));
  float* c      = (float*)alloc((size_t)B_ * S_ * sizeof(float));     // 128 KB
  float* pooled = (float*)alloc((size_t)B_ * D_ * sizeof(float));     // 64 KB
  float* hpre   = (float*)alloc((size_t)B_ * 4 * D_ * sizeof(float)); // 256 KB
  float* outpre = (float*)alloc((size_t)B_ * D_ * sizeof(float));     // 64 KB
  (void)ws_size; (void)in_sizes; (void)n_in; (void)out_size;

  // zero the atomic-accumulated buffers (contiguous region starting at c)
  const size_t zero_bytes = (size_t)B_ * S_ * 4 + (size_t)B_ * D_ * 4 +
                            (size_t)B_ * 4 * D_ * 4 + (size_t)B_ * D_ * 4;
  hipMemsetAsync(c, 0, zero_bytes, stream);

  k_pack_bias<<<12, 256, 0, stream>>>(bq, bk, bv, biasQKV);
  k_transpose_cvt<<<dim3(32, 32), 256, 0, stream>>>(Wq, Wt);
  k_transpose_cvt<<<dim3(32, 32), 256, 0, stream>>>(Wk, Wt + (size_t)D_ * D_);
  k_transpose_cvt<<<dim3(32, 32), 256, 0, stream>>>(Wv, Wt + 2 * (size_t)D_ * D_);

  // QKV: C[m,n] = X[m,:] @ W[:,n] + b[n]; z = 0,1,2 selects (Wq,bq,Q), (Wk,bk,K), (Wv,bv,V)
  k_gemm_bt<true, true><<<dim3(D_ / 128, (B_ * S_) / 128, 3), 256, 0, stream>>>(
      (const void*)X, Wt, biasQKV, QKVb,
      B_ * S_, D_, D_, 1.0f,
      /*sA_z=*/0, /*sB_z=*/(long long)D_ * D_, /*sC_z=*/BSD, /*biasStride=*/D_);

  // scores[b,q,k] = (Q[b,q,:] . K[b,k,:]) / 32
  k_gemm_bt<false, false><<<dim3(S_ / 128, S_ / 128, B_), 256, 0, stream>>>(
      (const void*)Qb, Kb, nullptr, Sc,
      S_, S_, D_, 0.03125f,
      (long long)S_ * D_, (long long)S_ * D_, (long long)S_ * S_, 0);

  k_softmax_colsum<<<dim3(S_ / 32, B_), 256, 0, stream>>>(Sc, mask, c);
  k_cv<<<dim3(S_ / 256, B_), 256, 0, stream>>>(c, Vb, pooled);
  k_mlp1<<<dim3(16, 4), 256, 0, stream>>>(pooled, W1, hpre);
  k_mlp2<<<dim3(4, 16), 256, 0, stream>>>(hpre, b1, W2, outpre);
  k_finish<<<64, 256, 0, stream>>>(outpre, b2, out);
}

// Round 2
// 748.556 us; speedup vs baseline: 1.5068x; 1.5068x over previous
//
#include <hip/hip_runtime.h>
#include <hip/hip_bf16.h>

constexpr int B_ = 16;
constexpr int S_ = 2048;
constexpr int D_ = 1024;
constexpr long long BSD = (long long)B_ * S_ * D_;   // 33,554,432

typedef unsigned short u16;
typedef __bf16 bf16x8 __attribute__((ext_vector_type(8)));
typedef float    f32x4 __attribute__((ext_vector_type(4)));
typedef unsigned short usx8 __attribute__((ext_vector_type(8)));
typedef unsigned short usx4 __attribute__((ext_vector_type(4)));

__device__ inline u16 f2b(float f) {            // f32 -> bf16 RNE
  unsigned u = __float_as_uint(f);
  u = (u + 0x7fffu + ((u >> 16) & 1u)) >> 16;
  return (u16)u;
}
__device__ inline float b2f(u16 v) { return __uint_as_float(((unsigned)v) << 16); }

__device__ __forceinline__ void gll16(const void* g, void* l) {
  __builtin_amdgcn_global_load_lds(
      (const __attribute__((address_space(1))) void*)g,
      (__attribute__((address_space(3))) void*)l, 16, 0, 0);
}

// ---------------- bias pack: [bq|bk|bv] -> contiguous ----------------
__global__ void k_pack_bias(const float* __restrict__ bq, const float* __restrict__ bk,
                            const float* __restrict__ bv, float* __restrict__ dst) {
  int t = blockIdx.x * 256 + threadIdx.x;          // 3072 threads
  if (t < 1024) dst[t] = bq[t];
  else if (t < 2048) dst[t] = bk[t - 1024];
  else dst[t] = bv[t - 2048];
}

// ---------------- pack attention mask into bits: pmask[b*64 + w], bit j = mask[b][w*32+j]
__global__ void k_pack_mask(const int* __restrict__ mask, unsigned* __restrict__ pmask) {
  int t = blockIdx.x * 256 + threadIdx.x;          // 1024 threads
  if (t >= B_ * 64) return;
  int b = t >> 6, w = t & 63;
  unsigned bits = 0;
#pragma unroll
  for (int j = 0; j < 32; j++) bits |= (mask[b * S_ + w * 32 + j] != 0 ? 1u : 0u) << j;
  pmask[t] = bits;
}

// ---------------- X f32 -> bf16 ----------------
__global__ __launch_bounds__(256) void k_cvt_x(const float* __restrict__ X,
                                               u16* __restrict__ Xb) {
  size_t i = ((size_t)blockIdx.x * 256 + threadIdx.x) * 8;
  f32x4 a = *(const f32x4*)(X + i);
  f32x4 b = *(const f32x4*)(X + i + 4);
  usx8 o;
  o[0] = f2b(a[0]); o[1] = f2b(a[1]); o[2] = f2b(a[2]); o[3] = f2b(a[3]);
  o[4] = f2b(b[0]); o[5] = f2b(b[1]); o[6] = f2b(b[2]); o[7] = f2b(b[3]);
  *(usx8*)(Xb + i) = o;
}

// ---------------- transpose+convert W[k][n] (f32) -> Wt[n][k] (bf16) ----------------
__global__ __launch_bounds__(256) void k_transpose_cvt(const float* __restrict__ W,
                                                       u16* __restrict__ Wt) {
  __shared__ float tile[32][33];
  const int n0 = blockIdx.x * 32, k0 = blockIdx.y * 32;
  const int tx = threadIdx.x & 31, ty = threadIdx.x >> 5;   // ty 0..7
  for (int r = ty; r < 32; r += 8)
    tile[r][tx] = W[(size_t)(k0 + r) * D_ + n0 + tx];
  __syncthreads();
  for (int r = ty; r < 32; r += 8)
    Wt[(size_t)(n0 + r) * D_ + k0 + tx] = f2b(tile[tx][r]);
}

// ---------------- GEMM (B-transposed): C[m,n] = scale * sum_k A[m,k]*Bt[n,k] (+ bias[n])
// m97 structure: 128x128 tile, BK=64, 4 waves, global_load_lds w16, linear LDS, XCD swizzle
template <bool BIAS>
__global__ __launch_bounds__(256) void k_gemm_bt(
    const u16* __restrict__ A, const u16* __restrict__ Bt,
    const float* __restrict__ bias, u16* __restrict__ C,
    int N, int K, float scale,
    long long sA_z, long long sB_z, long long sC_z, int biasStride) {
  constexpr int BM = 128, BN = 128, BK = 64;
  __shared__ u16 sA[BM * BK];
  __shared__ u16 sB[BN * BK];
  const int tid = threadIdx.x;
  const int lane = tid & 63, wave = tid >> 6;

  // ---- XCD-aware bijective swizzle (nwg % 8 == 0 for all our grids) ----
  const int gx = gridDim.x, gy = gridDim.y;
  const int nwg = gx * gy * gridDim.z;
  const int orig = blockIdx.x + gx * (blockIdx.y + gy * blockIdx.z);
  const int cpx = nwg >> 3;
  const int tile = (orig & 7) * cpx + (orig >> 3);
  const int bx = tile % gx;
  const int rest = tile / gx;
  const int by = rest % gy;
  const int bz = rest / gy;

  const u16* Az = A + (size_t)bz * sA_z;
  const u16* Bz = Bt + (size_t)bz * sB_z;
  u16* Cz = C + (size_t)bz * sC_z;
  const int m0 = by * BM, n0 = bx * BN;
  const int wm = (wave >> 1) * 64, wn = (wave & 1) * 64;

  // staging: wave w stages rows [w*32, w*32+32) of both tiles; 4 issues x 8 rows
  const int srow = wave * 32 + (lane >> 3);   // + t*8 per issue
  const int scol = (lane & 7) * 8;
  const u16* gA = Az + (size_t)(m0 + srow) * K + scol;
  const u16* gB = Bz + (size_t)(n0 + srow) * K + scol;
  u16* lA = sA + wave * 32 * BK;              // wave-uniform; HW adds lane*16B
  u16* lB = sB + wave * 32 * BK;

  f32x4 acc[4][4] = {};

  for (int kt = 0; kt < K; kt += BK) {
#pragma unroll
    for (int t = 0; t < 4; t++) {
      gll16(gA + kt + (size_t)t * 8 * K, lA + t * 8 * BK);
      gll16(gB + kt + (size_t)t * 8 * K, lB + t * 8 * BK);
    }
    __syncthreads();   // drains vmcnt(0) then barrier
#pragma unroll
    for (int kk = 0; kk < BK; kk += 32) {
      bf16x8 af[4], bfr[4];
#pragma unroll
      for (int i = 0; i < 4; i++)
        af[i] = *(const bf16x8*)(sA + (wm + i * 16 + (lane & 15)) * BK + kk + (lane >> 4) * 8);
#pragma unroll
      for (int j = 0; j < 4; j++)
        bfr[j] = *(const bf16x8*)(sB + (wn + j * 16 + (lane & 15)) * BK + kk + (lane >> 4) * 8);
#pragma unroll
      for (int i = 0; i < 4; i++)
#pragma unroll
        for (int j = 0; j < 4; j++)
          acc[i][j] = __builtin_amdgcn_mfma_f32_16x16x32_bf16(af[i], bfr[j], acc[i][j], 0, 0, 0);
    }
    __syncthreads();
  }
  // epilogue: C/D layout col = lane&15, row = (lane>>4)*4 + r
#pragma unroll
  for (int i = 0; i < 4; i++) {
    const int r0 = m0 + wm + i * 16 + ((lane >> 4) << 2);
#pragma unroll
    for (int j = 0; j < 4; j++) {
      const int col = n0 + wn + j * 16 + (lane & 15);
      const float badd = BIAS ? bias[bz * biasStride + col] : 0.0f;
#pragma unroll
      for (int r = 0; r < 4; r++) {
        float v = acc[i][j][r] * scale + badd;
        Cz[(size_t)(r0 + r) * N + col] = f2b(v);
      }
    }
  }
}

// ---------------- softmax rows + column-sum: c[b,k] += (1/S) * sum_q softmax(scores[b,q,:])[k]
// Each lane owns cols [lane*32, lane*32+32); per-wave register accumulation.
__global__ __launch_bounds__(256) void k_softmax_colsum(
    const u16* __restrict__ scores, const unsigned* __restrict__ pmask,
    float* __restrict__ c) {
  __shared__ float colsum[S_];
  const int b = blockIdx.y;
  const int r0 = blockIdx.x * 32;            // 32 rows per block, 8 per wave
  const int tid = threadIdx.x, lane = tid & 63, wave = tid >> 6;
  for (int k = tid; k < S_; k += 256) colsum[k] = 0.0f;
  __syncthreads();

  const unsigned mb = pmask[b * 64 + lane];  // bit i <-> col lane*32+i
  const u16* base = scores + ((size_t)b * S_ + r0 + wave * 8) * S_ + lane * 32;
  float csum[32];
#pragma unroll
  for (int i = 0; i < 32; i++) csum[i] = 0.0f;

  for (int rr = 0; rr < 8; rr++) {
    const u16* srow = base + (size_t)rr * S_;
    float s[32];
    float m = -1e30f;
#pragma unroll
    for (int v = 0; v < 4; v++) {
      usx8 x = *(const usx8*)(srow + v * 8);
#pragma unroll
      for (int e = 0; e < 8; e++) {
        const int i = v * 8 + e;
        float val = ((mb >> i) & 1u) ? b2f(x[e]) : -1e30f;
        s[i] = val;
        m = fmaxf(m, val);
      }
    }
#pragma unroll
    for (int o = 1; o < 64; o <<= 1) m = fmaxf(m, __shfl_xor(m, o));
    float sum = 0.f;
#pragma unroll
    for (int i = 0; i < 32; i++) { s[i] = __expf(s[i] - m); sum += s[i]; }
#pragma unroll
    for (int o = 1; o < 64; o <<= 1) sum += __shfl_xor(sum, o);
    const float inv = 1.0f / (sum * (float)S_);
#pragma unroll
    for (int i = 0; i < 32; i++) csum[i] += s[i] * inv;
  }
  // bank-conflict-free LDS accumulate: rotate index by lane
#pragma unroll
  for (int i = 0; i < 32; i++) {
    const int j = (i + lane) & 31;
    atomicAdd(&colsum[lane * 32 + j], csum[j]);
  }
  __syncthreads();
  for (int k = tid; k < S_; k += 256) atomicAdd(&c[b * S_ + k], colsum[k]);
}

// ---------------- pooled[b,d] = sum_k c[b,k] * V[b,k,d]
__global__ __launch_bounds__(256) void k_cv(const float* __restrict__ c,
                                            const u16* __restrict__ Vb,
                                            float* __restrict__ pooled) {
  const int b = blockIdx.y;
  const int k0 = blockIdx.x * 64;
  const int tid = threadIdx.x;
  f32x4 acc = {};
  const u16* vb = Vb + ((size_t)b * S_ + k0) * D_ + tid * 4;
  const float* cb = c + b * S_ + k0;
  for (int k = 0; k < 64; k++) {
    const float w = cb[k];
    usx4 v = *(const usx4*)(vb + (size_t)k * D_);
    acc[0] += w * b2f(v[0]);
    acc[1] += w * b2f(v[1]);
    acc[2] += w * b2f(v[2]);
    acc[3] += w * b2f(v[3]);
  }
#pragma unroll
  for (int q = 0; q < 4; q++) atomicAdd(&pooled[b * D_ + tid * 4 + q], acc[q]);
}

// ---------------- hpre = pooled @ W1 (atomically accumulated)
__global__ __launch_bounds__(256) void k_mlp1(const float* __restrict__ pooled,
                                              const float* __restrict__ W1,
                                              float* __restrict__ hpre) {
  __shared__ float ps[16][256];
  const int tid = threadIdx.x;
  const int j = blockIdx.x * 256 + tid;
  const int i0 = blockIdx.y * 256;
  for (int x = tid; x < 16 * 256; x += 256) {
    const int bb = x >> 8, ii = x & 255;
    ps[bb][ii] = pooled[bb * D_ + i0 + ii];
  }
  __syncthreads();
  float acc[16] = {};
  for (int i = 0; i < 256; i++) {
    const float w = W1[(size_t)(i0 + i) * (4 * D_) + j];
#pragma unroll
    for (int bb = 0; bb < 16; bb++) acc[bb] += ps[bb][i] * w;
  }
#pragma unroll
  for (int bb = 0; bb < 16; bb++) atomicAdd(&hpre[bb * (4 * D_) + j], acc[bb]);
}

// ---------------- outpre = relu(hpre + b1) @ W2 (atomically accumulated)
__global__ __launch_bounds__(256) void k_mlp2(const float* __restrict__ hpre,
                                              const float* __restrict__ b1,
                                              const float* __restrict__ W2,
                                              float* __restrict__ outpre) {
  __shared__ float hs[16][256];
  const int tid = threadIdx.x;
  const int n = blockIdx.x * 256 + tid;
  const int i0 = blockIdx.y * 256;
  for (int x = tid; x < 16 * 256; x += 256) {
    const int bb = x >> 8, ii = x & 255;
    hs[bb][ii] = fmaxf(hpre[bb * (4 * D_) + i0 + ii] + b1[i0 + ii], 0.0f);
  }
  __syncthreads();
  float acc[16] = {};
  for (int i = 0; i < 256; i++) {
    const float w = W2[(size_t)(i0 + i) * D_ + n];
#pragma unroll
    for (int bb = 0; bb < 16; bb++) acc[bb] += hs[bb][i] * w;
  }
#pragma unroll
  for (int bb = 0; bb < 16; bb++) atomicAdd(&outpre[bb * D_ + n], acc[bb]);
}

// ---------------- out = tanh(outpre + b2)
__global__ void k_finish(const float* __restrict__ outpre, const float* __restrict__ b2,
                         float* __restrict__ out) {
  const int x = blockIdx.x * 256 + threadIdx.x;   // 16384
  out[x] = tanhf(outpre[x] + b2[x & (D_ - 1)]);
}

extern "C" void kernel_launch(void* const* d_in, const int* in_sizes, int n_in,
                              void* d_out, int out_size, void* d_ws, size_t ws_size,
                              hipStream_t stream) {
  const float* X  = (const float*)d_in[0];
  const int* mask = (const int*)d_in[1];
  const float* Wq = (const float*)d_in[2];
  const float* bq = (const float*)d_in[3];
  const float* Wk = (const float*)d_in[4];
  const float* bk = (const float*)d_in[5];
  const float* Wv = (const float*)d_in[6];
  const float* bv = (const float*)d_in[7];
  const float* W1 = (const float*)d_in[8];
  const float* b1 = (const float*)d_in[9];
  const float* W2 = (const float*)d_in[10];
  const float* b2 = (const float*)d_in[11];
  float* out = (float*)d_out;

  char* ws = (char*)d_ws;
  size_t off = 0;
  auto alloc = [&](size_t bytes) -> void* {
    void* p = ws + off;
    off += (bytes + 255) & ~(size_t)255;
    return p;
  };
  u16* QKVb = (u16*)alloc(3 * BSD * sizeof(u16));                 // 192 MB: Q|K|V bf16
  u16* Qb = QKVb;
  u16* Kb = QKVb + BSD;
  u16* Vb = QKVb + 2 * BSD;
  u16* Sc = (u16*)alloc((size_t)B_ * S_ * S_ * sizeof(u16));      // 128 MB scores bf16
  u16* Xb = Sc;   // X-bf16 (64 MB) aliases Sc: consumed by QKV gemm before Sc is written
  u16* Wt = (u16*)alloc((size_t)3 * D_ * D_ * sizeof(u16));       // 6 MB
  float* biasQKV = (float*)alloc(3 * D_ * sizeof(float));
  unsigned* pmask = (unsigned*)alloc((size_t)B_ * 64 * sizeof(unsigned));
  float* c      = (float*)alloc((size_t)B_ * S_ * sizeof(float));     // 128 KB
  float* pooled = (float*)alloc((size_t)B_ * D_ * sizeof(float));     // 64 KB
  float* hpre   = (float*)alloc((size_t)B_ * 4 * D_ * sizeof(float)); // 256 KB
  float* outpre = (float*)alloc((size_t)B_ * D_ * sizeof(float));     // 64 KB
  (void)ws_size; (void)in_sizes; (void)n_in; (void)out_size;

  const size_t zero_bytes = (size_t)B_ * S_ * 4 + (size_t)B_ * D_ * 4 +
                            (size_t)B_ * 4 * D_ * 4 + (size_t)B_ * D_ * 4;
  hipMemsetAsync(c, 0, zero_bytes, stream);

  k_pack_bias<<<12, 256, 0, stream>>>(bq, bk, bv, biasQKV);
  k_pack_mask<<<4, 256, 0, stream>>>(mask, pmask);
  k_cvt_x<<<(int)(BSD / 8 / 256), 256, 0, stream>>>(X, Xb);
  k_transpose_cvt<<<dim3(32, 32), 256, 0, stream>>>(Wq, Wt);
  k_transpose_cvt<<<dim3(32, 32), 256, 0, stream>>>(Wk, Wt + (size_t)D_ * D_);
  k_transpose_cvt<<<dim3(32, 32), 256, 0, stream>>>(Wv, Wt + 2 * (size_t)D_ * D_);

  // QKV: z selects (Wq,bq,Q), (Wk,bk,K), (Wv,bv,V); A = Xb shared (sA_z = 0)
  k_gemm_bt<true><<<dim3(D_ / 128, (B_ * S_) / 128, 3), 256, 0, stream>>>(
      Xb, Wt, biasQKV, QKVb,
      D_, D_, 1.0f,
      /*sA_z=*/0, /*sB_z=*/(long long)D_ * D_, /*sC_z=*/BSD, /*biasStride=*/D_);

  // scores[b,q,k] = (Q[b,q,:] . K[b,k,:]) / 32    (overwrites the Xb alias — safe, stream-ordered)
  k_gemm_bt<false><<<dim3(S_ / 128, S_ / 128, B_), 256, 0, stream>>>(
      Qb, Kb, nullptr, Sc,
      S_, D_, 0.03125f,
      (long long)S_ * D_, (long long)S_ * D_, (long long)S_ * S_, 0);

  k_softmax_colsum<<<dim3(S_ / 32, B_), 256, 0, stream>>>(Sc, pmask, c);
  k_cv<<<dim3(S_ / 64, B_), 256, 0, stream>>>(c, Vb, pooled);
  k_mlp1<<<dim3(16, 4), 256, 0, stream>>>(pooled, W1, hpre);
  k_mlp2<<<dim3(4, 16), 256, 0, stream>>>(hpre, b1, W2, outpre);
  k_finish<<<64, 256, 0, stream>>>(outpre, b2, out);
}

// Round 3
// 582.874 us; speedup vs baseline: 1.9352x; 1.2843x over previous
//
#include <hip/hip_runtime.h>
#include <hip/hip_bf16.h>

constexpr int B_ = 16;
constexpr int S_ = 2048;
constexpr int D_ = 1024;
constexpr long long BSD = (long long)B_ * S_ * D_;   // 33,554,432

typedef unsigned short u16;
typedef __bf16 bf16x8 __attribute__((ext_vector_type(8)));
typedef float    f32x4 __attribute__((ext_vector_type(4)));
typedef unsigned short usx8 __attribute__((ext_vector_type(8)));
typedef unsigned short usx4 __attribute__((ext_vector_type(4)));

__device__ inline u16 f2b(float f) {            // f32 -> bf16 RNE
  unsigned u = __float_as_uint(f);
  u = (u + 0x7fffu + ((u >> 16) & 1u)) >> 16;
  return (u16)u;
}
__device__ inline float b2f(u16 v) { return __uint_as_float(((unsigned)v) << 16); }

__device__ __forceinline__ void gll16(const void* g, void* l) {
  __builtin_amdgcn_global_load_lds(
      (const __attribute__((address_space(1))) void*)g,
      (__attribute__((address_space(3))) void*)l, 16, 0, 0);
}

__device__ __forceinline__ void vmwait8() {
  asm volatile("s_waitcnt vmcnt(8)" ::: "memory");
  __builtin_amdgcn_sched_barrier(0);
}
__device__ __forceinline__ void vmwait4() {
  asm volatile("s_waitcnt vmcnt(4)" ::: "memory");
  __builtin_amdgcn_sched_barrier(0);
}
__device__ __forceinline__ void vmwait0() {
  asm volatile("s_waitcnt vmcnt(0)" ::: "memory");
  __builtin_amdgcn_sched_barrier(0);
}
__device__ __forceinline__ void lgkm0() {
  asm volatile("s_waitcnt lgkmcnt(0)" ::: "memory");
  __builtin_amdgcn_sched_barrier(0);
}
__device__ __forceinline__ void barrier_pin() {
  __builtin_amdgcn_sched_barrier(0);
  __builtin_amdgcn_s_barrier();
  __builtin_amdgcn_sched_barrier(0);
}

// ---------------- bias pack: [bq|bk|bv] -> contiguous ----------------
__global__ void k_pack_bias(const float* __restrict__ bq, const float* __restrict__ bk,
                            const float* __restrict__ bv, float* __restrict__ dst) {
  int t = blockIdx.x * 256 + threadIdx.x;          // 3072 threads
  if (t < 1024) dst[t] = bq[t];
  else if (t < 2048) dst[t] = bk[t - 1024];
  else dst[t] = bv[t - 2048];
}

// ---------------- pack attention mask into bits: pmask[b*64 + w], bit j = mask[b][w*32+j]
__global__ void k_pack_mask(const int* __restrict__ mask, unsigned* __restrict__ pmask) {
  int t = blockIdx.x * 256 + threadIdx.x;          // 1024 threads
  if (t >= B_ * 64) return;
  int b = t >> 6, w = t & 63;
  unsigned bits = 0;
#pragma unroll
  for (int j = 0; j < 32; j++) bits |= (mask[b * S_ + w * 32 + j] != 0 ? 1u : 0u) << j;
  pmask[t] = bits;
}

// ---------------- X f32 -> bf16 ----------------
__global__ __launch_bounds__(256) void k_cvt_x(const float* __restrict__ X,
                                               u16* __restrict__ Xb) {
  size_t i = ((size_t)blockIdx.x * 256 + threadIdx.x) * 8;
  f32x4 a = *(const f32x4*)(X + i);
  f32x4 b = *(const f32x4*)(X + i + 4);
  usx8 o;
  o[0] = f2b(a[0]); o[1] = f2b(a[1]); o[2] = f2b(a[2]); o[3] = f2b(a[3]);
  o[4] = f2b(b[0]); o[5] = f2b(b[1]); o[6] = f2b(b[2]); o[7] = f2b(b[3]);
  *(usx8*)(Xb + i) = o;
}

// ---------------- transpose+convert W[k][n] (f32) -> Wt[n][k] (bf16) ----------------
__global__ __launch_bounds__(256) void k_transpose_cvt(const float* __restrict__ W,
                                                       u16* __restrict__ Wt) {
  __shared__ float tile[32][33];
  const int n0 = blockIdx.x * 32, k0 = blockIdx.y * 32;
  const int tx = threadIdx.x & 31, ty = threadIdx.x >> 5;   // ty 0..7
  for (int r = ty; r < 32; r += 8)
    tile[r][tx] = W[(size_t)(k0 + r) * D_ + n0 + tx];
  __syncthreads();
  for (int r = ty; r < 32; r += 8)
    Wt[(size_t)(n0 + r) * D_ + k0 + tx] = f2b(tile[tx][r]);
}

// =====================================================================
// 256x256 fine-interleaved pipelined GEMM (B-transposed), K=1024 fixed.
// 512 threads = 8 waves (2M x 4N), per-wave output 128x64.
// BK=32 -> 32 K-tiles; LDS ring of 4 K-tile buffers (128 KiB dynamic).
// Per tile: 2 phases x {ds_read frags | 2x global_load_lds (tile t+3) |
//   barrier | lgkmcnt(0) | setprio(1) 16 MFMA setprio(0)}; counted
//   vmcnt(8/4/0) at tile end only (never drained mid-loop).
// LDS swizzle: 16B-slot ^= (row&3)^((row>>2)&3), applied to global src
// (inverse) and ds_read addr (same involution); linear gll dest.
// =====================================================================
template <bool QKV>
__global__ __launch_bounds__(512, 2) void k_gemm8(
    const u16* __restrict__ A, const u16* __restrict__ Bt,
    const float* __restrict__ bias, u16* __restrict__ C,
    float scale, long long sA_z, long long sB_z, long long sC_z) {
  extern __shared__ u16 sm[];            // 4 * (A:8192 | B:8192) u16 = 128 KiB
  constexpr int NT = 32;                 // 1024 / 32
  const int tid = threadIdx.x, lane = tid & 63, wave = tid >> 6;

  // XCD-aware bijective swizzle (nwg % 8 == 0 for both grids)
  const int gx = gridDim.x, gy = gridDim.y;
  const int nwg = gx * gy * gridDim.z;
  const int orig = blockIdx.x + gx * (blockIdx.y + gy * blockIdx.z);
  const int cpx = nwg >> 3;
  const int tl = (orig & 7) * cpx + (orig >> 3);
  const int bx = tl % gx;
  const int rest = tl / gx;
  const int by = rest % gy;
  const int bz = rest / gy;

  const u16* Az = A + (size_t)bz * sA_z;
  const u16* Bz = Bt + (size_t)bz * sB_z;
  const int m0 = by * 256, n0 = bx * 256;
  const int wm = (wave >> 2) * 128, wn = (wave & 3) * 64;

  // staging: thread covers row = q*128 + wave*16 + (lane>>2), 16B slot (lane&3)
  const int srow = wave * 16 + (lane >> 2);
  const int sslot = (lane & 3) ^ ((lane >> 2) & 3) ^ (lane >> 4);  // pre-swizzled source slot
  const u16* gA = Az + (size_t)(m0 + srow) * 1024 + sslot * 8;
  const u16* gB = Bz + (size_t)(n0 + srow) * 1024 + sslot * 8;
  const int lbase = wave * 512;          // u16; q=1 adds 4096

  // frag ds_read offsets (u16 units); swizzled slot
  const int fslot = (lane >> 4) ^ (lane & 3) ^ ((lane >> 2) & 3);
  const int aoff = (wm + (lane & 15)) * 32 + fslot * 8;
  const int boff = (wn + (lane & 15)) * 32 + fslot * 8;

  f32x4 acc[8][4] = {};

  auto stageA = [&](int t) {
    u16* la = sm + (t & 3) * 16384 + lbase;
    const u16* g = gA + t * 32;
    gll16(g, la);
    gll16(g + (size_t)128 * 1024, la + 4096);
  };
  auto stageB = [&](int t) {
    u16* lb = sm + (t & 3) * 16384 + 8192 + lbase;
    const u16* g = gB + t * 32;
    gll16(g, lb);
    gll16(g + (size_t)128 * 1024, lb + 4096);
  };

  // prologue: stage tiles 0,1,2 (12 loads in flight)
  stageA(0); stageB(0);
  stageA(1); stageB(1);
  stageA(2); stageB(2);
  vmwait8();                 // tile 0 landed (own wave)
  barrier_pin();             // -> landed for all waves

#pragma unroll 4
  for (int t = 0; t < NT; ++t) {
    const u16* bufA = sm + (t & 3) * 16384;
    const u16* bufB = bufA + 8192;
    bf16x8 b0, b1, b2, b3;
    // ---- phase 1: M-frags 0..3 x N-frags 0..3 ----
    {
      bf16x8 a[4];
#pragma unroll
      for (int i = 0; i < 4; ++i)
        a[i] = *(const bf16x8*)(bufA + aoff + i * 512);
      b0 = *(const bf16x8*)(bufB + boff);
      b1 = *(const bf16x8*)(bufB + boff + 512);
      b2 = *(const bf16x8*)(bufB + boff + 1024);
      b3 = *(const bf16x8*)(bufB + boff + 1536);
      if (t <= NT - 4) stageA(t + 3);
      barrier_pin();
      lgkm0();
      __builtin_amdgcn_s_setprio(1);
#pragma unroll
      for (int i = 0; i < 4; ++i) {
        acc[i][0] = __builtin_amdgcn_mfma_f32_16x16x32_bf16(a[i], b0, acc[i][0], 0, 0, 0);
        acc[i][1] = __builtin_amdgcn_mfma_f32_16x16x32_bf16(a[i], b1, acc[i][1], 0, 0, 0);
        acc[i][2] = __builtin_amdgcn_mfma_f32_16x16x32_bf16(a[i], b2, acc[i][2], 0, 0, 0);
        acc[i][3] = __builtin_amdgcn_mfma_f32_16x16x32_bf16(a[i], b3, acc[i][3], 0, 0, 0);
      }
      __builtin_amdgcn_s_setprio(0);
      barrier_pin();
    }
    // ---- phase 2: M-frags 4..7 x N-frags 0..3 (B regs reused) ----
    {
      bf16x8 a[4];
#pragma unroll
      for (int i = 0; i < 4; ++i)
        a[i] = *(const bf16x8*)(bufA + aoff + 2048 + i * 512);
      if (t <= NT - 4) stageB(t + 3);
      barrier_pin();
      lgkm0();
      __builtin_amdgcn_s_setprio(1);
#pragma unroll
      for (int i = 0; i < 4; ++i) {
        acc[i + 4][0] = __builtin_amdgcn_mfma_f32_16x16x32_bf16(a[i], b0, acc[i + 4][0], 0, 0, 0);
        acc[i + 4][1] = __builtin_amdgcn_mfma_f32_16x16x32_bf16(a[i], b1, acc[i + 4][1], 0, 0, 0);
        acc[i + 4][2] = __builtin_amdgcn_mfma_f32_16x16x32_bf16(a[i], b2, acc[i + 4][2], 0, 0, 0);
        acc[i + 4][3] = __builtin_amdgcn_mfma_f32_16x16x32_bf16(a[i], b3, acc[i + 4][3], 0, 0, 0);
      }
      __builtin_amdgcn_s_setprio(0);
      // end-of-tile: ensure tile t+1 landed before next tile's reads
      if (t <= NT - 4) vmwait8();
      else if (t == NT - 3) vmwait4();
      else if (t == NT - 2) vmwait0();
      barrier_pin();
    }
  }

  // epilogue: C/D layout col = lane&15, row = (lane>>4)*4 + r
#pragma unroll
  for (int i = 0; i < 8; ++i) {
    const int row = m0 + wm + i * 16 + ((lane >> 4) << 2);
#pragma unroll
    for (int j = 0; j < 4; ++j) {
      const int col = n0 + wn + j * 16 + (lane & 15);
      if (QKV) {
        const float badd = bias[col];
        u16* cp = C + (size_t)(col >> 10) * sC_z + (size_t)row * 1024 + (col & 1023);
#pragma unroll
        for (int r = 0; r < 4; ++r) cp[(size_t)r * 1024] = f2b(acc[i][j][r] + badd);
      } else {
        u16* cp = C + (size_t)bz * sC_z + (size_t)row * 2048 + col;
#pragma unroll
        for (int r = 0; r < 4; ++r) cp[(size_t)r * 2048] = f2b(acc[i][j][r] * scale);
      }
    }
  }
}

// ---------------- softmax rows + column-sum: c[b,k] += (1/S) * sum_q softmax(scores[b,q,:])[k]
__global__ __launch_bounds__(256) void k_softmax_colsum(
    const u16* __restrict__ scores, const unsigned* __restrict__ pmask,
    float* __restrict__ c) {
  __shared__ float colsum[S_];
  const int b = blockIdx.y;
  const int r0 = blockIdx.x * 32;            // 32 rows per block, 8 per wave
  const int tid = threadIdx.x, lane = tid & 63, wave = tid >> 6;
  for (int k = tid; k < S_; k += 256) colsum[k] = 0.0f;
  __syncthreads();

  const unsigned mb = pmask[b * 64 + lane];  // bit i <-> col lane*32+i
  const u16* base = scores + ((size_t)b * S_ + r0 + wave * 8) * S_ + lane * 32;
  float csum[32];
#pragma unroll
  for (int i = 0; i < 32; i++) csum[i] = 0.0f;

  for (int rr = 0; rr < 8; rr++) {
    const u16* srow = base + (size_t)rr * S_;
    float s[32];
    float m = -1e30f;
#pragma unroll
    for (int v = 0; v < 4; v++) {
      usx8 x = *(const usx8*)(srow + v * 8);
#pragma unroll
      for (int e = 0; e < 8; e++) {
        const int i = v * 8 + e;
        float val = ((mb >> i) & 1u) ? b2f(x[e]) : -1e30f;
        s[i] = val;
        m = fmaxf(m, val);
      }
    }
#pragma unroll
    for (int o = 1; o < 64; o <<= 1) m = fmaxf(m, __shfl_xor(m, o));
    float sum = 0.f;
#pragma unroll
    for (int i = 0; i < 32; i++) { s[i] = __expf(s[i] - m); sum += s[i]; }
#pragma unroll
    for (int o = 1; o < 64; o <<= 1) sum += __shfl_xor(sum, o);
    const float inv = 1.0f / (sum * (float)S_);
#pragma unroll
    for (int i = 0; i < 32; i++) csum[i] += s[i] * inv;
  }
#pragma unroll
  for (int i = 0; i < 32; i++) {
    const int j = (i + lane) & 31;
    atomicAdd(&colsum[lane * 32 + j], csum[j]);
  }
  __syncthreads();
  for (int k = tid; k < S_; k += 256) atomicAdd(&c[b * S_ + k], colsum[k]);
}

// ---------------- pooled[b,d] = sum_k c[b,k] * V[b,k,d]
__global__ __launch_bounds__(256) void k_cv(const float* __restrict__ c,
                                            const u16* __restrict__ Vb,
                                            float* __restrict__ pooled) {
  const int b = blockIdx.y;
  const int k0 = blockIdx.x * 64;
  const int tid = threadIdx.x;
  f32x4 acc = {};
  const u16* vb = Vb + ((size_t)b * S_ + k0) * D_ + tid * 4;
  const float* cb = c + b * S_ + k0;
  for (int k = 0; k < 64; k++) {
    const float w = cb[k];
    usx4 v = *(const usx4*)(vb + (size_t)k * D_);
    acc[0] += w * b2f(v[0]);
    acc[1] += w * b2f(v[1]);
    acc[2] += w * b2f(v[2]);
    acc[3] += w * b2f(v[3]);
  }
#pragma unroll
  for (int q = 0; q < 4; q++) atomicAdd(&pooled[b * D_ + tid * 4 + q], acc[q]);
}

// ---------------- hpre = pooled @ W1 (atomically accumulated)
__global__ __launch_bounds__(256) void k_mlp1(const float* __restrict__ pooled,
                                              const float* __restrict__ W1,
                                              float* __restrict__ hpre) {
  __shared__ float ps[16][256];
  const int tid = threadIdx.x;
  const int j = blockIdx.x * 256 + tid;
  const int i0 = blockIdx.y * 256;
  for (int x = tid; x < 16 * 256; x += 256) {
    const int bb = x >> 8, ii = x & 255;
    ps[bb][ii] = pooled[bb * D_ + i0 + ii];
  }
  __syncthreads();
  float acc[16] = {};
  for (int i = 0; i < 256; i++) {
    const float w = W1[(size_t)(i0 + i) * (4 * D_) + j];
#pragma unroll
    for (int bb = 0; bb < 16; bb++) acc[bb] += ps[bb][i] * w;
  }
#pragma unroll
  for (int bb = 0; bb < 16; bb++) atomicAdd(&hpre[bb * (4 * D_) + j], acc[bb]);
}

// ---------------- outpre = relu(hpre + b1) @ W2 (atomically accumulated)
__global__ __launch_bounds__(256) void k_mlp2(const float* __restrict__ hpre,
                                              const float* __restrict__ b1,
                                              const float* __restrict__ W2,
                                              float* __restrict__ outpre) {
  __shared__ float hs[16][256];
  const int tid = threadIdx.x;
  const int n = blockIdx.x * 256 + tid;
  const int i0 = blockIdx.y * 256;
  for (int x = tid; x < 16 * 256; x += 256) {
    const int bb = x >> 8, ii = x & 255;
    hs[bb][ii] = fmaxf(hpre[bb * (4 * D_) + i0 + ii] + b1[i0 + ii], 0.0f);
  }
  __syncthreads();
  float acc[16] = {};
  for (int i = 0; i < 256; i++) {
    const float w = W2[(size_t)(i0 + i) * D_ + n];
#pragma unroll
    for (int bb = 0; bb < 16; bb++) acc[bb] += hs[bb][i] * w;
  }
#pragma unroll
  for (int bb = 0; bb < 16; bb++) atomicAdd(&outpre[bb * D_ + n], acc[bb]);
}

// ---------------- out = tanh(outpre + b2)
__global__ void k_finish(const float* __restrict__ outpre, const float* __restrict__ b2,
                         float* __restrict__ out) {
  const int x = blockIdx.x * 256 + threadIdx.x;   // 16384
  out[x] = tanhf(outpre[x] + b2[x & (D_ - 1)]);
}

extern "C" void kernel_launch(void* const* d_in, const int* in_sizes, int n_in,
                              void* d_out, int out_size, void* d_ws, size_t ws_size,
                              hipStream_t stream) {
  const float* X  = (const float*)d_in[0];
  const int* mask = (const int*)d_in[1];
  const float* Wq = (const float*)d_in[2];
  const float* bq = (const float*)d_in[3];
  const float* Wk = (const float*)d_in[4];
  const float* bk = (const float*)d_in[5];
  const float* Wv = (const float*)d_in[6];
  const float* bv = (const float*)d_in[7];
  const float* W1 = (const float*)d_in[8];
  const float* b1 = (const float*)d_in[9];
  const float* W2 = (const float*)d_in[10];
  const float* b2 = (const float*)d_in[11];
  float* out = (float*)d_out;

  char* ws = (char*)d_ws;
  size_t off = 0;
  auto alloc = [&](size_t bytes) -> void* {
    void* p = ws + off;
    off += (bytes + 255) & ~(size_t)255;
    return p;
  };
  u16* QKVb = (u16*)alloc(3 * BSD * sizeof(u16));                 // 192 MB: Q|K|V bf16
  u16* Qb = QKVb;
  u16* Kb = QKVb + BSD;
  u16* Vb = QKVb + 2 * BSD;
  u16* Sc = (u16*)alloc((size_t)B_ * S_ * S_ * sizeof(u16));      // 128 MB scores bf16
  u16* Xb = Sc;   // X-bf16 (64 MB) aliases Sc: consumed by QKV gemm before Sc is written
  u16* Wt = (u16*)alloc((size_t)3 * D_ * D_ * sizeof(u16));       // 6 MB: [3072][1024]
  float* biasQKV = (float*)alloc(3 * D_ * sizeof(float));
  unsigned* pmask = (unsigned*)alloc((size_t)B_ * 64 * sizeof(unsigned));
  float* c      = (float*)alloc((size_t)B_ * S_ * sizeof(float));     // 128 KB
  float* pooled = (float*)alloc((size_t)B_ * D_ * sizeof(float));     // 64 KB
  float* hpre   = (float*)alloc((size_t)B_ * 4 * D_ * sizeof(float)); // 256 KB
  float* outpre = (float*)alloc((size_t)B_ * D_ * sizeof(float));     // 64 KB
  (void)ws_size; (void)in_sizes; (void)n_in; (void)out_size;

  const size_t zero_bytes = (size_t)B_ * S_ * 4 + (size_t)B_ * D_ * 4 +
                            (size_t)B_ * 4 * D_ * 4 + (size_t)B_ * D_ * 4;
  hipMemsetAsync(c, 0, zero_bytes, stream);

  k_pack_bias<<<12, 256, 0, stream>>>(bq, bk, bv, biasQKV);
  k_pack_mask<<<4, 256, 0, stream>>>(mask, pmask);
  k_cvt_x<<<(int)(BSD / 8 / 256), 256, 0, stream>>>(X, Xb);
  k_transpose_cvt<<<dim3(32, 32), 256, 0, stream>>>(Wq, Wt);
  k_transpose_cvt<<<dim3(32, 32), 256, 0, stream>>>(Wk, Wt + (size_t)D_ * D_);
  k_transpose_cvt<<<dim3(32, 32), 256, 0, stream>>>(Wv, Wt + 2 * (size_t)D_ * D_);

  // merged QKV: C[m, n<3072] = Xb[m,:] @ Wt[n,:] + bias[n]; output split per 1024-col group
  k_gemm8<true><<<dim3(3072 / 256, (B_ * S_) / 256, 1), 512, 131072, stream>>>(
      Xb, Wt, biasQKV, QKVb, 1.0f,
      /*sA_z=*/0, /*sB_z=*/0, /*sC_z=*/BSD);

  // scores[b,q,k] = (Q[b,q,:] . K[b,k,:]) / 32   (overwrites the Xb alias — stream-ordered)
  k_gemm8<false><<<dim3(S_ / 256, S_ / 256, B_), 512, 131072, stream>>>(
      Qb, Kb, nullptr, Sc, 0.03125f,
      (long long)S_ * D_, (long long)S_ * D_, (long long)S_ * S_);

  k_softmax_colsum<<<dim3(S_ / 32, B_), 256, 0, stream>>>(Sc, pmask, c);
  k_cv<<<dim3(S_ / 64, B_), 256, 0, stream>>>(c, Vb, pooled);
  k_mlp1<<<dim3(16, 4), 256, 0, stream>>>(pooled, W1, hpre);
  k_mlp2<<<dim3(4, 16), 256, 0, stream>>>(hpre, b1, W2, outpre);
  k_finish<<<64, 256, 0, stream>>>(outpre, b2, out);
}

// Round 4
// 577.443 us; speedup vs baseline: 1.9534x; 1.0094x over previous
//
#include <hip/hip_runtime.h>
#include <hip/hip_bf16.h>

constexpr int B_ = 16;
constexpr int S_ = 2048;
constexpr int D_ = 1024;
constexpr long long BSD = (long long)B_ * S_ * D_;   // 33,554,432

typedef unsigned short u16;
typedef __bf16 bf16x8 __attribute__((ext_vector_type(8)));
typedef float    f32x4 __attribute__((ext_vector_type(4)));
typedef unsigned short usx8 __attribute__((ext_vector_type(8)));
typedef unsigned short usx4 __attribute__((ext_vector_type(4)));

__device__ inline u16 f2b(float f) {            // f32 -> bf16 RNE
  unsigned u = __float_as_uint(f);
  u = (u + 0x7fffu + ((u >> 16) & 1u)) >> 16;
  return (u16)u;
}
__device__ inline float b2f(u16 v) { return __uint_as_float(((unsigned)v) << 16); }

__device__ __forceinline__ void gll16(const void* g, void* l) {
  __builtin_amdgcn_global_load_lds(
      (const __attribute__((address_space(1))) void*)g,
      (__attribute__((address_space(3))) void*)l, 16, 0, 0);
}

__device__ __forceinline__ void vmwait4() {
  asm volatile("s_waitcnt vmcnt(4)" ::: "memory");
  __builtin_amdgcn_sched_barrier(0);
}
__device__ __forceinline__ void vmwait0() {
  asm volatile("s_waitcnt vmcnt(0)" ::: "memory");
  __builtin_amdgcn_sched_barrier(0);
}
__device__ __forceinline__ void lgkm12() {
  asm volatile("s_waitcnt lgkmcnt(12)" ::: "memory");
  __builtin_amdgcn_sched_barrier(0);
}
__device__ __forceinline__ void lgkm8() {
  asm volatile("s_waitcnt lgkmcnt(8)" ::: "memory");
  __builtin_amdgcn_sched_barrier(0);
}
__device__ __forceinline__ void lgkm4() {
  asm volatile("s_waitcnt lgkmcnt(4)" ::: "memory");
  __builtin_amdgcn_sched_barrier(0);
}
__device__ __forceinline__ void lgkm0w() {
  asm volatile("s_waitcnt lgkmcnt(0)" ::: "memory");
  __builtin_amdgcn_sched_barrier(0);
}
__device__ __forceinline__ void barrier_pin() {
  __builtin_amdgcn_sched_barrier(0);
  __builtin_amdgcn_s_barrier();
  __builtin_amdgcn_sched_barrier(0);
}

// ---------------- bias pack ----------------
__global__ void k_pack_bias(const float* __restrict__ bq, const float* __restrict__ bk,
                            const float* __restrict__ bv, float* __restrict__ dst) {
  int t = blockIdx.x * 256 + threadIdx.x;
  if (t < 1024) dst[t] = bq[t];
  else if (t < 2048) dst[t] = bk[t - 1024];
  else dst[t] = bv[t - 2048];
}

// ---------------- pack attention mask into bits ----------------
__global__ void k_pack_mask(const int* __restrict__ mask, unsigned* __restrict__ pmask) {
  int t = blockIdx.x * 256 + threadIdx.x;
  if (t >= B_ * 64) return;
  int b = t >> 6, w = t & 63;
  unsigned bits = 0;
#pragma unroll
  for (int j = 0; j < 32; j++) bits |= (mask[b * S_ + w * 32 + j] != 0 ? 1u : 0u) << j;
  pmask[t] = bits;
}

// ---------------- X f32 -> bf16 ----------------
__global__ __launch_bounds__(256) void k_cvt_x(const float* __restrict__ X,
                                               u16* __restrict__ Xb) {
  size_t i = ((size_t)blockIdx.x * 256 + threadIdx.x) * 8;
  f32x4 a = *(const f32x4*)(X + i);
  f32x4 b = *(const f32x4*)(X + i + 4);
  usx8 o;
  o[0] = f2b(a[0]); o[1] = f2b(a[1]); o[2] = f2b(a[2]); o[3] = f2b(a[3]);
  o[4] = f2b(b[0]); o[5] = f2b(b[1]); o[6] = f2b(b[2]); o[7] = f2b(b[3]);
  *(usx8*)(Xb + i) = o;
}

// ---------------- transpose+convert W[k][n] (f32) -> Wt[n][k] (bf16) ----------------
__global__ __launch_bounds__(256) void k_transpose_cvt(const float* __restrict__ W,
                                                       u16* __restrict__ Wt) {
  __shared__ float tile[32][33];
  const int n0 = blockIdx.x * 32, k0 = blockIdx.y * 32;
  const int tx = threadIdx.x & 31, ty = threadIdx.x >> 5;
  for (int r = ty; r < 32; r += 8)
    tile[r][tx] = W[(size_t)(k0 + r) * D_ + n0 + tx];
  __syncthreads();
  for (int r = ty; r < 32; r += 8)
    Wt[(size_t)(n0 + r) * D_ + k0 + tx] = f2b(tile[tx][r]);
}

// =====================================================================
// 256x256 deep-pipelined GEMM (B-transposed), K=1024.
// 512 thr = 8 waves (2M x 4N), per-wave 128x64. BK=32, 4-deep LDS ring.
// Per iter t: {4 ds_read A2(t) | 8 ds_read B/A1(t+1) | 4 gll stage(t+3) |
//   lgkm(12) | 16 MFMA | lgkm(8) | 16 MFMA | vmcnt(4) | barrier}.
// LDS reads drain DURING the MFMA window (one-tile-ahead frag prefetch);
// reads stay in flight across the barrier. Counted lgkm relies on
// in-order DS retirement (m218 pattern).
// =====================================================================
#define GBODY(T, CB, CA, NB, NA, W35, W5, DO_NEXT)                              \
  {                                                                             \
    const int t_ = (T);                                                         \
    const u16* cbuf = sm + (t_ & 3) * 16384;                                    \
    bf16x8 a2[4];                                                               \
    _Pragma("unroll")                                                           \
    for (int i = 0; i < 4; ++i)                                                 \
      a2[i] = *(const bf16x8*)(cbuf + aoff + 2048 + i * 512);                   \
    __builtin_amdgcn_sched_barrier(0);                                          \
    if (DO_NEXT) {                                                              \
      const u16* nbuf = sm + ((t_ + 1) & 3) * 16384;                            \
      _Pragma("unroll")                                                         \
      for (int j = 0; j < 4; ++j)                                               \
        NB[j] = *(const bf16x8*)(nbuf + 8192 + boff + j * 512);                 \
      _Pragma("unroll")                                                         \
      for (int i = 0; i < 4; ++i)                                               \
        NA[i] = *(const bf16x8*)(nbuf + aoff + i * 512);                        \
    }                                                                           \
    __builtin_amdgcn_sched_barrier(0);                                          \
    if (t_ <= NT - 4) { stageA(t_ + 3); stageB(t_ + 3); }                       \
    W35();                                                                      \
    __builtin_amdgcn_s_setprio(1);                                              \
    _Pragma("unroll")                                                           \
    for (int i = 0; i < 4; ++i) {                                               \
      acc[i][0] = __builtin_amdgcn_mfma_f32_16x16x32_bf16(CA[i], CB[0], acc[i][0], 0, 0, 0); \
      acc[i][1] = __builtin_amdgcn_mfma_f32_16x16x32_bf16(CA[i], CB[1], acc[i][1], 0, 0, 0); \
      acc[i][2] = __builtin_amdgcn_mfma_f32_16x16x32_bf16(CA[i], CB[2], acc[i][2], 0, 0, 0); \
      acc[i][3] = __builtin_amdgcn_mfma_f32_16x16x32_bf16(CA[i], CB[3], acc[i][3], 0, 0, 0); \
    }                                                                           \
    __builtin_amdgcn_s_setprio(0);                                              \
    W5();                                                                       \
    __builtin_amdgcn_s_setprio(1);                                              \
    _Pragma("unroll")                                                           \
    for (int i = 0; i < 4; ++i) {                                               \
      acc[i + 4][0] = __builtin_amdgcn_mfma_f32_16x16x32_bf16(a2[i], CB[0], acc[i + 4][0], 0, 0, 0); \
      acc[i + 4][1] = __builtin_amdgcn_mfma_f32_16x16x32_bf16(a2[i], CB[1], acc[i + 4][1], 0, 0, 0); \
      acc[i + 4][2] = __builtin_amdgcn_mfma_f32_16x16x32_bf16(a2[i], CB[2], acc[i + 4][2], 0, 0, 0); \
      acc[i + 4][3] = __builtin_amdgcn_mfma_f32_16x16x32_bf16(a2[i], CB[3], acc[i + 4][3], 0, 0, 0); \
    }                                                                           \
    __builtin_amdgcn_s_setprio(0);                                              \
    if (t_ <= NT - 4) vmwait4();                                                \
    else if (t_ == NT - 3) vmwait0();                                           \
    barrier_pin();                                                              \
  }

template <bool QKV>
__global__ __launch_bounds__(512, 2) void k_gemm8(
    const u16* __restrict__ A, const u16* __restrict__ Bt,
    const float* __restrict__ bias, u16* __restrict__ C,
    float scale, long long sA_z, long long sB_z, long long sC_z) {
  extern __shared__ u16 sm[];            // 4 * (A:8192 | B:8192) u16 = 128 KiB
  constexpr int NT = 32;                 // 1024 / 32
  const int tid = threadIdx.x, lane = tid & 63, wave = tid >> 6;

  // XCD-aware bijective swizzle (nwg % 8 == 0 for both grids)
  const int gx = gridDim.x, gy = gridDim.y;
  const int nwg = gx * gy * gridDim.z;
  const int orig = blockIdx.x + gx * (blockIdx.y + gy * blockIdx.z);
  const int cpx = nwg >> 3;
  const int tl = (orig & 7) * cpx + (orig >> 3);
  const int bx = tl % gx;
  const int rest = tl / gx;
  const int by = rest % gy;
  const int bz = rest / gy;

  const u16* Az = A + (size_t)bz * sA_z;
  const u16* Bz = Bt + (size_t)bz * sB_z;
  const int m0 = by * 256, n0 = bx * 256;
  const int wm = (wave >> 2) * 128, wn = (wave & 3) * 64;

  // staging: thread covers row = q*128 + wave*16 + (lane>>2), 16B slot (lane&3)
  const int srow = wave * 16 + (lane >> 2);
  const int sslot = (lane & 3) ^ ((lane >> 2) & 3) ^ (lane >> 4);  // pre-swizzled source
  const u16* gA = Az + (size_t)(m0 + srow) * 1024 + sslot * 8;
  const u16* gB = Bz + (size_t)(n0 + srow) * 1024 + sslot * 8;
  const int lbase = wave * 512;          // u16; q=1 adds 4096

  // frag ds_read offsets (u16 units); swizzled slot
  const int fslot = (lane >> 4) ^ (lane & 3) ^ ((lane >> 2) & 3);
  const int aoff = (wm + (lane & 15)) * 32 + fslot * 8;
  const int boff = (wn + (lane & 15)) * 32 + fslot * 8;

  f32x4 acc[8][4] = {};

  auto stageA = [&](int t) {
    u16* la = sm + (t & 3) * 16384 + lbase;
    const u16* g = gA + t * 32;
    gll16(g, la);
    gll16(g + (size_t)128 * 1024, la + 4096);
  };
  auto stageB = [&](int t) {
    u16* lb = sm + (t & 3) * 16384 + 8192 + lbase;
    const u16* g = gB + t * 32;
    gll16(g, lb);
    gll16(g + (size_t)128 * 1024, lb + 4096);
  };

  // prologue: stage tiles 0,1,2; wait tiles 0,1; read tile-0 frags
  stageA(0); stageB(0);
  stageA(1); stageB(1);
  stageA(2); stageB(2);
  vmwait4();                 // tiles 0,1 landed (own wave)
  barrier_pin();             // -> landed for all waves

  bf16x8 B0[4], A0[4], B1[4], A1r[4];
#pragma unroll
  for (int j = 0; j < 4; ++j) B0[j] = *(const bf16x8*)(sm + 8192 + boff + j * 512);
#pragma unroll
  for (int i = 0; i < 4; ++i) A0[i] = *(const bf16x8*)(sm + aoff + i * 512);
  __builtin_amdgcn_sched_barrier(0);

  for (int t = 0; t < NT - 2; t += 2) {
    GBODY(t,     B0, A0,  B1, A1r, lgkm12, lgkm8, 1)
    GBODY(t + 1, B1, A1r, B0, A0,  lgkm12, lgkm8, 1)
  }
  GBODY(NT - 2, B0, A0,  B1, A1r, lgkm12, lgkm8, 1)
  GBODY(NT - 1, B1, A1r, B0, A0,  lgkm4,  lgkm0w, 0)

  // epilogue: C/D layout col = lane&15, row = (lane>>4)*4 + r
#pragma unroll
  for (int i = 0; i < 8; ++i) {
    const int row = m0 + wm + i * 16 + ((lane >> 4) << 2);
#pragma unroll
    for (int j = 0; j < 4; ++j) {
      const int col = n0 + wn + j * 16 + (lane & 15);
      if (QKV) {
        const float badd = bias[col];
        u16* cp = C + (size_t)(col >> 10) * sC_z + (size_t)row * 1024 + (col & 1023);
#pragma unroll
        for (int r = 0; r < 4; ++r) cp[(size_t)r * 1024] = f2b(acc[i][j][r] + badd);
      } else {
        u16* cp = C + (size_t)bz * sC_z + (size_t)row * 2048 + col;
#pragma unroll
        for (int r = 0; r < 4; ++r) cp[(size_t)r * 2048] = f2b(acc[i][j][r] * scale);
      }
    }
  }
}

// ---------------- softmax rows + column-sum ----------------
__global__ __launch_bounds__(256) void k_softmax_colsum(
    const u16* __restrict__ scores, const unsigned* __restrict__ pmask,
    float* __restrict__ c) {
  __shared__ float colsum[S_];
  const int b = blockIdx.y;
  const int r0 = blockIdx.x * 32;
  const int tid = threadIdx.x, lane = tid & 63, wave = tid >> 6;
  for (int k = tid; k < S_; k += 256) colsum[k] = 0.0f;
  __syncthreads();

  const unsigned mb = pmask[b * 64 + lane];
  const u16* base = scores + ((size_t)b * S_ + r0 + wave * 8) * S_ + lane * 32;
  float csum[32];
#pragma unroll
  for (int i = 0; i < 32; i++) csum[i] = 0.0f;

  for (int rr = 0; rr < 8; rr++) {
    const u16* srow = base + (size_t)rr * S_;
    float s[32];
    float m = -1e30f;
#pragma unroll
    for (int v = 0; v < 4; v++) {
      usx8 x = *(const usx8*)(srow + v * 8);
#pragma unroll
      for (int e = 0; e < 8; e++) {
        const int i = v * 8 + e;
        float val = ((mb >> i) & 1u) ? b2f(x[e]) : -1e30f;
        s[i] = val;
        m = fmaxf(m, val);
      }
    }
#pragma unroll
    for (int o = 1; o < 64; o <<= 1) m = fmaxf(m, __shfl_xor(m, o));
    float sum = 0.f;
#pragma unroll
    for (int i = 0; i < 32; i++) { s[i] = __expf(s[i] - m); sum += s[i]; }
#pragma unroll
    for (int o = 1; o < 64; o <<= 1) sum += __shfl_xor(sum, o);
    const float inv = 1.0f / (sum * (float)S_);
#pragma unroll
    for (int i = 0; i < 32; i++) csum[i] += s[i] * inv;
  }
#pragma unroll
  for (int i = 0; i < 32; i++) {
    const int j = (i + lane) & 31;
    atomicAdd(&colsum[lane * 32 + j], csum[j]);
  }
  __syncthreads();
  for (int k = tid; k < S_; k += 256) atomicAdd(&c[b * S_ + k], colsum[k]);
}

// ---------------- pooled[b,d] = sum_k c[b,k] * V[b,k,d]
__global__ __launch_bounds__(256) void k_cv(const float* __restrict__ c,
                                            const u16* __restrict__ Vb,
                                            float* __restrict__ pooled) {
  const int b = blockIdx.y;
  const int k0 = blockIdx.x * 64;
  const int tid = threadIdx.x;
  f32x4 acc = {};
  const u16* vb = Vb + ((size_t)b * S_ + k0) * D_ + tid * 4;
  const float* cb = c + b * S_ + k0;
  for (int k = 0; k < 64; k++) {
    const float w = cb[k];
    usx4 v = *(const usx4*)(vb + (size_t)k * D_);
    acc[0] += w * b2f(v[0]);
    acc[1] += w * b2f(v[1]);
    acc[2] += w * b2f(v[2]);
    acc[3] += w * b2f(v[3]);
  }
#pragma unroll
  for (int q = 0; q < 4; q++) atomicAdd(&pooled[b * D_ + tid * 4 + q], acc[q]);
}

// ---------------- hpre = pooled @ W1
__global__ __launch_bounds__(256) void k_mlp1(const float* __restrict__ pooled,
                                              const float* __restrict__ W1,
                                              float* __restrict__ hpre) {
  __shared__ float ps[16][256];
  const int tid = threadIdx.x;
  const int j = blockIdx.x * 256 + tid;
  const int i0 = blockIdx.y * 256;
  for (int x = tid; x < 16 * 256; x += 256) {
    const int bb = x >> 8, ii = x & 255;
    ps[bb][ii] = pooled[bb * D_ + i0 + ii];
  }
  __syncthreads();
  float acc[16] = {};
  for (int i = 0; i < 256; i++) {
    const float w = W1[(size_t)(i0 + i) * (4 * D_) + j];
#pragma unroll
    for (int bb = 0; bb < 16; bb++) acc[bb] += ps[bb][i] * w;
  }
#pragma unroll
  for (int bb = 0; bb < 16; bb++) atomicAdd(&hpre[bb * (4 * D_) + j], acc[bb]);
}

// ---------------- outpre = relu(hpre + b1) @ W2
__global__ __launch_bounds__(256) void k_mlp2(const float* __restrict__ hpre,
                                              const float* __restrict__ b1,
                                              const float* __restrict__ W2,
                                              float* __restrict__ outpre) {
  __shared__ float hs[16][256];
  const int tid = threadIdx.x;
  const int n = blockIdx.x * 256 + tid;
  const int i0 = blockIdx.y * 256;
  for (int x = tid; x < 16 * 256; x += 256) {
    const int bb = x >> 8, ii = x & 255;
    hs[bb][ii] = fmaxf(hpre[bb * (4 * D_) + i0 + ii] + b1[i0 + ii], 0.0f);
  }
  __syncthreads();
  float acc[16] = {};
  for (int i = 0; i < 256; i++) {
    const float w = W2[(size_t)(i0 + i) * D_ + n];
#pragma unroll
    for (int bb = 0; bb < 16; bb++) acc[bb] += hs[bb][i] * w;
  }
#pragma unroll
  for (int bb = 0; bb < 16; bb++) atomicAdd(&outpre[bb * D_ + n], acc[bb]);
}

// ---------------- out = tanh(outpre + b2)
__global__ void k_finish(const float* __restrict__ outpre, const float* __restrict__ b2,
                         float* __restrict__ out) {
  const int x = blockIdx.x * 256 + threadIdx.x;
  out[x] = tanhf(outpre[x] + b2[x & (D_ - 1)]);
}

extern "C" void kernel_launch(void* const* d_in, const int* in_sizes, int n_in,
                              void* d_out, int out_size, void* d_ws, size_t ws_size,
                              hipStream_t stream) {
  const float* X  = (const float*)d_in[0];
  const int* mask = (const int*)d_in[1];
  const float* Wq = (const float*)d_in[2];
  const float* bq = (const float*)d_in[3];
  const float* Wk = (const float*)d_in[4];
  const float* bk = (const float*)d_in[5];
  const float* Wv = (const float*)d_in[6];
  const float* bv = (const float*)d_in[7];
  const float* W1 = (const float*)d_in[8];
  const float* b1 = (const float*)d_in[9];
  const float* W2 = (const float*)d_in[10];
  const float* b2 = (const float*)d_in[11];
  float* out = (float*)d_out;

  char* ws = (char*)d_ws;
  size_t off = 0;
  auto alloc = [&](size_t bytes) -> void* {
    void* p = ws + off;
    off += (bytes + 255) & ~(size_t)255;
    return p;
  };
  u16* QKVb = (u16*)alloc(3 * BSD * sizeof(u16));                 // 192 MB
  u16* Qb = QKVb;
  u16* Kb = QKVb + BSD;
  u16* Vb = QKVb + 2 * BSD;
  u16* Sc = (u16*)alloc((size_t)B_ * S_ * S_ * sizeof(u16));      // 128 MB
  u16* Xb = Sc;   // X-bf16 aliases Sc: consumed before Sc written
  u16* Wt = (u16*)alloc((size_t)3 * D_ * D_ * sizeof(u16));       // 6 MB
  float* biasQKV = (float*)alloc(3 * D_ * sizeof(float));
  unsigned* pmask = (unsigned*)alloc((size_t)B_ * 64 * sizeof(unsigned));
  float* c      = (float*)alloc((size_t)B_ * S_ * sizeof(float));
  float* pooled = (float*)alloc((size_t)B_ * D_ * sizeof(float));
  float* hpre   = (float*)alloc((size_t)B_ * 4 * D_ * sizeof(float));
  float* outpre = (float*)alloc((size_t)B_ * D_ * sizeof(float));
  (void)ws_size; (void)in_sizes; (void)n_in; (void)out_size;

  const size_t zero_bytes = (size_t)B_ * S_ * 4 + (size_t)B_ * D_ * 4 +
                            (size_t)B_ * 4 * D_ * 4 + (size_t)B_ * D_ * 4;
  hipMemsetAsync(c, 0, zero_bytes, stream);

  k_pack_bias<<<12, 256, 0, stream>>>(bq, bk, bv, biasQKV);
  k_pack_mask<<<4, 256, 0, stream>>>(mask, pmask);
  k_cvt_x<<<(int)(BSD / 8 / 256), 256, 0, stream>>>(X, Xb);
  k_transpose_cvt<<<dim3(32, 32), 256, 0, stream>>>(Wq, Wt);
  k_transpose_cvt<<<dim3(32, 32), 256, 0, stream>>>(Wk, Wt + (size_t)D_ * D_);
  k_transpose_cvt<<<dim3(32, 32), 256, 0, stream>>>(Wv, Wt + 2 * (size_t)D_ * D_);

  // merged QKV: C[m, n<3072] = Xb @ Wt + bias; output split per 1024-col group
  k_gemm8<true><<<dim3(3072 / 256, (B_ * S_) / 256, 1), 512, 131072, stream>>>(
      Xb, Wt, biasQKV, QKVb, 1.0f,
      /*sA_z=*/0, /*sB_z=*/0, /*sC_z=*/BSD);

  // scores[b,q,k] = (Q . K) / 32   (overwrites Xb alias — stream-ordered)
  k_gemm8<false><<<dim3(S_ / 256, S_ / 256, B_), 512, 131072, stream>>>(
      Qb, Kb, nullptr, Sc, 0.03125f,
      (long long)S_ * D_, (long long)S_ * D_, (long long)S_ * S_);

  k_softmax_colsum<<<dim3(S_ / 32, B_), 256, 0, stream>>>(Sc, pmask, c);
  k_cv<<<dim3(S_ / 64, B_), 256, 0, stream>>>(c, Vb, pooled);
  k_mlp1<<<dim3(16, 4), 256, 0, stream>>>(pooled, W1, hpre);
  k_mlp2<<<dim3(4, 16), 256, 0, stream>>>(hpre, b1, W2, outpre);
  k_finish<<<64, 256, 0, stream>>>(outpre, b2, out);
}

// Round 6
// 556.376 us; speedup vs baseline: 2.0273x; 1.0379x over previous
//
#include <hip/hip_runtime.h>
#include <hip/hip_bf16.h>

constexpr int B_ = 16;
constexpr int S_ = 2048;
constexpr int D_ = 1024;
constexpr long long BSD = (long long)B_ * S_ * D_;   // 33,554,432

typedef unsigned short u16;
typedef __bf16 bf16x8 __attribute__((ext_vector_type(8)));
typedef float    f32x4 __attribute__((ext_vector_type(4)));
typedef unsigned short usx8 __attribute__((ext_vector_type(8)));
typedef unsigned short usx4 __attribute__((ext_vector_type(4)));

__device__ inline u16 f2b(float f) {            // f32 -> bf16 RNE
  unsigned u = __float_as_uint(f);
  u = (u + 0x7fffu + ((u >> 16) & 1u)) >> 16;
  return (u16)u;
}
__device__ inline float b2f(u16 v) { return __uint_as_float(((unsigned)v) << 16); }

__device__ __forceinline__ void gll16(const void* g, void* l) {
  __builtin_amdgcn_global_load_lds(
      (const __attribute__((address_space(1))) void*)g,
      (__attribute__((address_space(3))) void*)l, 16, 0, 0);
}

__device__ __forceinline__ void vmwait4() {
  asm volatile("s_waitcnt vmcnt(4)" ::: "memory");
  __builtin_amdgcn_sched_barrier(0);
}
__device__ __forceinline__ void vmwait2() {
  asm volatile("s_waitcnt vmcnt(2)" ::: "memory");
  __builtin_amdgcn_sched_barrier(0);
}
__device__ __forceinline__ void vmwait0() {
  asm volatile("s_waitcnt vmcnt(0)" ::: "memory");
  __builtin_amdgcn_sched_barrier(0);
}
__device__ __forceinline__ void lgkm0w() {
  asm volatile("s_waitcnt lgkmcnt(0)" ::: "memory");
  __builtin_amdgcn_sched_barrier(0);
}
__device__ __forceinline__ void barrier_pin() {
  __builtin_amdgcn_sched_barrier(0);
  __builtin_amdgcn_s_barrier();
  __builtin_amdgcn_sched_barrier(0);
}

// ---------------- bias pack ----------------
__global__ void k_pack_bias(const float* __restrict__ bq, const float* __restrict__ bk,
                            const float* __restrict__ bv, float* __restrict__ dst) {
  int t = blockIdx.x * 256 + threadIdx.x;
  if (t < 1024) dst[t] = bq[t];
  else if (t < 2048) dst[t] = bk[t - 1024];
  else dst[t] = bv[t - 2048];
}

// ---------------- pack attention mask into bits ----------------
__global__ void k_pack_mask(const int* __restrict__ mask, unsigned* __restrict__ pmask) {
  int t = blockIdx.x * 256 + threadIdx.x;
  if (t >= B_ * 64) return;
  int b = t >> 6, w = t & 63;
  unsigned bits = 0;
#pragma unroll
  for (int j = 0; j < 32; j++) bits |= (mask[b * S_ + w * 32 + j] != 0 ? 1u : 0u) << j;
  pmask[t] = bits;
}

// ---------------- X f32 -> bf16 ----------------
__global__ __launch_bounds__(256) void k_cvt_x(const float* __restrict__ X,
                                               u16* __restrict__ Xb) {
  size_t i = ((size_t)blockIdx.x * 256 + threadIdx.x) * 8;
  f32x4 a = *(const f32x4*)(X + i);
  f32x4 b = *(const f32x4*)(X + i + 4);
  usx8 o;
  o[0] = f2b(a[0]); o[1] = f2b(a[1]); o[2] = f2b(a[2]); o[3] = f2b(a[3]);
  o[4] = f2b(b[0]); o[5] = f2b(b[1]); o[6] = f2b(b[2]); o[7] = f2b(b[3]);
  *(usx8*)(Xb + i) = o;
}

// ---------------- transpose+convert W[k][n] (f32) -> Wt[n][k] (bf16) ----------------
__global__ __launch_bounds__(256) void k_transpose_cvt(const float* __restrict__ W,
                                                       u16* __restrict__ Wt) {
  __shared__ float tile[32][33];
  const int n0 = blockIdx.x * 32, k0 = blockIdx.y * 32;
  const int tx = threadIdx.x & 31, ty = threadIdx.x >> 5;
  for (int r = ty; r < 32; r += 8)
    tile[r][tx] = W[(size_t)(k0 + r) * D_ + n0 + tx];
  __syncthreads();
  for (int r = ty; r < 32; r += 8)
    Wt[(size_t)(n0 + r) * D_ + k0 + tx] = f2b(tile[tx][r]);
}

// =====================================================================
// 256x256 8-phase GEMM (B-transposed), K=1024, BK=64, dbuf ring-2.
// 512 thr = 8 waves. Wave quadrants are GLOBAL-HALF aligned:
//   A quadrant MQ -> block rows MQ*128 + wm_i*64 + f*16 (part MQ for ALL waves)
//   B quadrant NQ -> block cols NQ*128 + wn_i*32 + n*16 (part 2+NQ for ALL waves)
// Phase reads: P0={A0,B0} P1={B1} P2={A1} P3={} (regs held).
// Stage slots (tile t+1): P0:A0 P1:B0 P2:B1 P3:A1.
// Certification (FIFO vmcnt, m135): vmwait4+barrier at P3(t-1) covers
//   P0(t)'s reads; P0(t) covers B1; P1(t) covers A1; P2 no wait.
// Tail tile: vmwait2 / vmwait0 / none / none. No full drain in loop.
// LDS swizzle: phys_slot = logical ^ (row&7); pre-swizzled gll SOURCE,
//   linear gll dest, swizzled ds_read (read bank load = uniform 8/bank).
// =====================================================================
#define READ_A(DD, MQ)                                                    \
  _Pragma("unroll")                                                       \
  for (int f = 0; f < 4; ++f) {                                           \
    const int ad = (DD) + (MQ) * 8192 + A_pre + f * 1024;                 \
    a_[f][0] = *(const bf16x8*)(sm + ad);                                 \
    a_[f][1] = *(const bf16x8*)(sm + (ad ^ 32));                          \
  }

#define READ_B(DD, NQ)                                                    \
  _Pragma("unroll")                                                       \
  for (int n = 0; n < 2; ++n) {                                           \
    const int bd = (DD) + 16384 + (NQ) * 8192 + B_pre + n * 1024;         \
    b_[NQ][n][0] = *(const bf16x8*)(sm + bd);                             \
    b_[NQ][n][1] = *(const bf16x8*)(sm + (bd ^ 32));                      \
  }

#define MFMA_Q(IO, JO, BQ)                                                \
  __builtin_amdgcn_s_setprio(1);                                         \
  _Pragma("unroll")                                                       \
  for (int kk = 0; kk < 2; ++kk)                                          \
    _Pragma("unroll")                                                     \
    for (int f = 0; f < 4; ++f)                                           \
      _Pragma("unroll")                                                   \
      for (int n = 0; n < 2; ++n)                                         \
        acc[(IO) + f][(JO) + n] = __builtin_amdgcn_mfma_f32_16x16x32_bf16(\
            a_[f][kk], b_[BQ][n][kk], acc[(IO) + f][(JO) + n], 0, 0, 0);  \
  __builtin_amdgcn_s_setprio(0);

template <bool QKV>
__global__ __launch_bounds__(512, 2) void k_gemm8(
    const u16* __restrict__ A, const u16* __restrict__ Bt,
    const float* __restrict__ bias, u16* __restrict__ C,
    float scale, long long sA_z, long long sB_z, long long sC_z) {
  extern __shared__ u16 sm[];            // 2 dbuf * 4 parts * 8192 u16 = 128 KiB
  constexpr int NT = 16;                 // 1024 / 64
  const int tid = threadIdx.x, lane = tid & 63, wave = tid >> 6;

  // XCD-aware bijective swizzle (nwg % 8 == 0 for both grids)
  const int gx = gridDim.x, gy = gridDim.y;
  const int nwg = gx * gy * gridDim.z;
  const int orig = blockIdx.x + gx * (blockIdx.y + gy * blockIdx.z);
  const int cpx = nwg >> 3;
  const int tl = (orig & 7) * cpx + (orig >> 3);
  const int bx = tl % gx;
  const int rest = tl / gx;
  const int by = rest % gy;
  const int bz = rest / gy;

  const u16* Az = A + (size_t)bz * sA_z;
  const u16* Bz = Bt + (size_t)bz * sB_z;
  const int m0 = by * 256, n0 = bx * 256;
  const int wm_i = wave >> 2, wn_i = wave & 3;

  // ---- staging (pre-swizzled global source; linear gll dest) ----
  const int grow = tid >> 3;                                   // 0..63
  const int gslot = ((tid & 7) ^ ((tid >> 3) & 7)) * 8;        // u16
  const u16* pA = Az + (size_t)(m0 + grow) * 1024 + gslot;
  const u16* pB = Bz + (size_t)(n0 + grow) * 1024 + gslot;

  auto stage_part = [&](int t, int part) {
    const u16* g0 = (part < 2 ? pA : pB) + (size_t)((part & 1) * 128) * 1024 + t * 64;
    u16* l0 = sm + (t & 1) * 32768 + part * 8192 + wave * 512;
    gll16(g0, l0);
    gll16(g0 + (size_t)64 * 1024, l0 + 4096);
  };

  // ---- read offsets (u16): phys_slot = logical ^ (row&7) ----
  const int r16 = lane & 15;
  const int s0k = (lane >> 4) ^ (lane & 7);
  const int A_pre = wm_i * 4096 + r16 * 64 + s0k * 8;   // + MQ*8192 + f*1024
  const int B_pre = wn_i * 2048 + r16 * 64 + s0k * 8;   // + 16384 + NQ*8192 + n*1024

  f32x4 acc[8][4] = {};
  bf16x8 a_[4][2], b_[2][2][2];

  // prologue: stage tile 0 in ledger order A0,B0,B1,A1; certify {A0,B0}
  stage_part(0, 0); stage_part(0, 2); stage_part(0, 3); stage_part(0, 1);
  vmwait4();
  barrier_pin();

#pragma unroll 1
  for (int t = 0; t < NT - 1; ++t) {
    const int DD = (t & 1) * 32768;
    // ---- P0: reads A0,B0; stage A0(t+1); certify B1(t)
    READ_A(DD, 0) READ_B(DD, 0)
    __builtin_amdgcn_sched_barrier(0);
    stage_part(t + 1, 0);
    vmwait4(); barrier_pin(); lgkm0w();
    MFMA_Q(0, 0, 0)
    barrier_pin();
    // ---- P1: reads B1; stage B0(t+1); certify A1(t)
    READ_B(DD, 1)
    __builtin_amdgcn_sched_barrier(0);
    stage_part(t + 1, 2);
    vmwait4(); barrier_pin(); lgkm0w();
    MFMA_Q(0, 2, 1)
    barrier_pin();
    // ---- P2: reads A1; stage B1(t+1); no wait needed
    READ_A(DD, 1)
    __builtin_amdgcn_sched_barrier(0);
    stage_part(t + 1, 3);
    barrier_pin(); lgkm0w();
    MFMA_Q(4, 2, 1)
    barrier_pin();
    // ---- P3: no reads; stage A1(t+1); certify {A0,B0}(t+1)
    stage_part(t + 1, 1);
    vmwait4(); barrier_pin();
    MFMA_Q(4, 0, 0)
    barrier_pin();
  }
  {  // ---- tail tile (no stages)
    const int DD = ((NT - 1) & 1) * 32768;
    READ_A(DD, 0) READ_B(DD, 0)
    vmwait2(); barrier_pin(); lgkm0w();
    MFMA_Q(0, 0, 0)
    barrier_pin();
    READ_B(DD, 1)
    vmwait0(); barrier_pin(); lgkm0w();
    MFMA_Q(0, 2, 1)
    barrier_pin();
    READ_A(DD, 1)
    barrier_pin(); lgkm0w();
    MFMA_Q(4, 2, 1)
    barrier_pin();
    MFMA_Q(4, 0, 0)
  }

  // epilogue: C/D layout col = lane&15, row = (lane>>4)*4 + r
#pragma unroll
  for (int i = 0; i < 8; ++i) {
    const int MQ = i >> 2, f = i & 3;
    const int row = m0 + MQ * 128 + wm_i * 64 + f * 16 + ((lane >> 4) << 2);
#pragma unroll
    for (int j = 0; j < 4; ++j) {
      const int NQ = j >> 1, n = j & 1;
      const int col = n0 + NQ * 128 + wn_i * 32 + n * 16 + (lane & 15);
      if (QKV) {
        const float badd = bias[col];
        u16* cp = C + (size_t)(col >> 10) * sC_z + (size_t)row * 1024 + (col & 1023);
#pragma unroll
        for (int r = 0; r < 4; ++r) cp[(size_t)r * 1024] = f2b(acc[i][j][r] + badd);
      } else {
        u16* cp = C + (size_t)bz * sC_z + (size_t)row * 2048 + col;
#pragma unroll
        for (int r = 0; r < 4; ++r) cp[(size_t)r * 2048] = f2b(acc[i][j][r] * scale);
      }
    }
  }
}

// ---------------- softmax rows + column-sum ----------------
__global__ __launch_bounds__(256) void k_softmax_colsum(
    const u16* __restrict__ scores, const unsigned* __restrict__ pmask,
    float* __restrict__ c) {
  __shared__ float colsum[S_];
  const int b = blockIdx.y;
  const int r0 = blockIdx.x * 32;
  const int tid = threadIdx.x, lane = tid & 63, wave = tid >> 6;
  for (int k = tid; k < S_; k += 256) colsum[k] = 0.0f;
  __syncthreads();

  const unsigned mb = pmask[b * 64 + lane];
  const u16* base = scores + ((size_t)b * S_ + r0 + wave * 8) * S_ + lane * 32;
  float csum[32];
#pragma unroll
  for (int i = 0; i < 32; i++) csum[i] = 0.0f;

  for (int rr = 0; rr < 8; rr++) {
    const u16* srow = base + (size_t)rr * S_;
    float s[32];
    float m = -1e30f;
#pragma unroll
    for (int v = 0; v < 4; v++) {
      usx8 x = *(const usx8*)(srow + v * 8);
#pragma unroll
      for (int e = 0; e < 8; e++) {
        const int i = v * 8 + e;
        float val = ((mb >> i) & 1u) ? b2f(x[e]) : -1e30f;
        s[i] = val;
        m = fmaxf(m, val);
      }
    }
#pragma unroll
    for (int o = 1; o < 64; o <<= 1) m = fmaxf(m, __shfl_xor(m, o));
    float sum = 0.f;
#pragma unroll
    for (int i = 0; i < 32; i++) { s[i] = __expf(s[i] - m); sum += s[i]; }
#pragma unroll
    for (int o = 1; o < 64; o <<= 1) sum += __shfl_xor(sum, o);
    const float inv = 1.0f / (sum * (float)S_);
#pragma unroll
    for (int i = 0; i < 32; i++) csum[i] += s[i] * inv;
  }
#pragma unroll
  for (int i = 0; i < 32; i++) {
    const int j = (i + lane) & 31;
    atomicAdd(&colsum[lane * 32 + j], csum[j]);
  }
  __syncthreads();
  for (int k = tid; k < S_; k += 256) atomicAdd(&c[b * S_ + k], colsum[k]);
}

// ---------------- pooled[b,d] = sum_k c[b,k] * V[b,k,d]
__global__ __launch_bounds__(256) void k_cv(const float* __restrict__ c,
                                            const u16* __restrict__ Vb,
                                            float* __restrict__ pooled) {
  const int b = blockIdx.y;
  const int k0 = blockIdx.x * 64;
  const int tid = threadIdx.x;
  f32x4 acc = {};
  const u16* vb = Vb + ((size_t)b * S_ + k0) * D_ + tid * 4;
  const float* cb = c + b * S_ + k0;
  for (int k = 0; k < 64; k++) {
    const float w = cb[k];
    usx4 v = *(const usx4*)(vb + (size_t)k * D_);
    acc[0] += w * b2f(v[0]);
    acc[1] += w * b2f(v[1]);
    acc[2] += w * b2f(v[2]);
    acc[3] += w * b2f(v[3]);
  }
#pragma unroll
  for (int q = 0; q < 4; q++) atomicAdd(&pooled[b * D_ + tid * 4 + q], acc[q]);
}

// ---------------- hpre = pooled @ W1
__global__ __launch_bounds__(256) void k_mlp1(const float* __restrict__ pooled,
                                              const float* __restrict__ W1,
                                              float* __restrict__ hpre) {
  __shared__ float ps[16][256];
  const int tid = threadIdx.x;
  const int j = blockIdx.x * 256 + tid;
  const int i0 = blockIdx.y * 256;
  for (int x = tid; x < 16 * 256; x += 256) {
    const int bb = x >> 8, ii = x & 255;
    ps[bb][ii] = pooled[bb * D_ + i0 + ii];
  }
  __syncthreads();
  float acc[16] = {};
  for (int i = 0; i < 256; i++) {
    const float w = W1[(size_t)(i0 + i) * (4 * D_) + j];
#pragma unroll
    for (int bb = 0; bb < 16; bb++) acc[bb] += ps[bb][i] * w;
  }
#pragma unroll
  for (int bb = 0; bb < 16; bb++) atomicAdd(&hpre[bb * (4 * D_) + j], acc[bb]);
}

// ---------------- outpre = relu(hpre + b1) @ W2
__global__ __launch_bounds__(256) void k_mlp2(const float* __restrict__ hpre,
                                              const float* __restrict__ b1,
                                              const float* __restrict__ W2,
                                              float* __restrict__ outpre) {
  __shared__ float hs[16][256];
  const int tid = threadIdx.x;
  const int n = blockIdx.x * 256 + tid;
  const int i0 = blockIdx.y * 256;
  for (int x = tid; x < 16 * 256; x += 256) {
    const int bb = x >> 8, ii = x & 255;
    hs[bb][ii] = fmaxf(hpre[bb * (4 * D_) + i0 + ii] + b1[i0 + ii], 0.0f);
  }
  __syncthreads();
  float acc[16] = {};
  for (int i = 0; i < 256; i++) {
    const float w = W2[(size_t)(i0 + i) * D_ + n];
#pragma unroll
    for (int bb = 0; bb < 16; bb++) acc[bb] += hs[bb][i] * w;
  }
#pragma unroll
  for (int bb = 0; bb < 16; bb++) atomicAdd(&outpre[bb * D_ + n], acc[bb]);
}

// ---------------- out = tanh(outpre + b2)
__global__ void k_finish(const float* __restrict__ outpre, const float* __restrict__ b2,
                         float* __restrict__ out) {
  const int x = blockIdx.x * 256 + threadIdx.x;
  out[x] = tanhf(outpre[x] + b2[x & (D_ - 1)]);
}

extern "C" void kernel_launch(void* const* d_in, const int* in_sizes, int n_in,
                              void* d_out, int out_size, void* d_ws, size_t ws_size,
                              hipStream_t stream) {
  const float* X  = (const float*)d_in[0];
  const int* mask = (const int*)d_in[1];
  const float* Wq = (const float*)d_in[2];
  const float* bq = (const float*)d_in[3];
  const float* Wk = (const float*)d_in[4];
  const float* bk = (const float*)d_in[5];
  const float* Wv = (const float*)d_in[6];
  const float* bv = (const float*)d_in[7];
  const float* W1 = (const float*)d_in[8];
  const float* b1 = (const float*)d_in[9];
  const float* W2 = (const float*)d_in[10];
  const float* b2 = (const float*)d_in[11];
  float* out = (float*)d_out;

  char* ws = (char*)d_ws;
  size_t off = 0;
  auto alloc = [&](size_t bytes) -> void* {
    void* p = ws + off;
    off += (bytes + 255) & ~(size_t)255;
    return p;
  };
  u16* QKVb = (u16*)alloc(3 * BSD * sizeof(u16));                 // 192 MB
  u16* Qb = QKVb;
  u16* Kb = QKVb + BSD;
  u16* Vb = QKVb + 2 * BSD;
  u16* Sc = (u16*)alloc((size_t)B_ * S_ * S_ * sizeof(u16));      // 128 MB
  u16* Xb = Sc;   // X-bf16 aliases Sc: consumed before Sc written
  u16* Wt = (u16*)alloc((size_t)3 * D_ * D_ * sizeof(u16));       // 6 MB
  float* biasQKV = (float*)alloc(3 * D_ * sizeof(float));
  unsigned* pmask = (unsigned*)alloc((size_t)B_ * 64 * sizeof(unsigned));
  float* c      = (float*)alloc((size_t)B_ * S_ * sizeof(float));
  float* pooled = (float*)alloc((size_t)B_ * D_ * sizeof(float));
  float* hpre   = (float*)alloc((size_t)B_ * 4 * D_ * sizeof(float));
  float* outpre = (float*)alloc((size_t)B_ * D_ * sizeof(float));
  (void)ws_size; (void)in_sizes; (void)n_in; (void)out_size;

  const size_t zero_bytes = (size_t)B_ * S_ * 4 + (size_t)B_ * D_ * 4 +
                            (size_t)B_ * 4 * D_ * 4 + (size_t)B_ * D_ * 4;
  hipMemsetAsync(c, 0, zero_bytes, stream);

  k_pack_bias<<<12, 256, 0, stream>>>(bq, bk, bv, biasQKV);
  k_pack_mask<<<4, 256, 0, stream>>>(mask, pmask);
  k_cvt_x<<<(int)(BSD / 8 / 256), 256, 0, stream>>>(X, Xb);
  k_transpose_cvt<<<dim3(32, 32), 256, 0, stream>>>(Wq, Wt);
  k_transpose_cvt<<<dim3(32, 32), 256, 0, stream>>>(Wk, Wt + (size_t)D_ * D_);
  k_transpose_cvt<<<dim3(32, 32), 256, 0, stream>>>(Wv, Wt + 2 * (size_t)D_ * D_);

  // merged QKV: C[m, n<3072] = Xb @ Wt + bias; output split per 1024-col group
  k_gemm8<true><<<dim3(3072 / 256, (B_ * S_) / 256, 1), 512, 131072, stream>>>(
      Xb, Wt, biasQKV, QKVb, 1.0f,
      /*sA_z=*/0, /*sB_z=*/0, /*sC_z=*/BSD);

  // scores[b,q,k] = (Q . K) / 32   (overwrites Xb alias — stream-ordered)
  k_gemm8<false><<<dim3(S_ / 256, S_ / 256, B_), 512, 131072, stream>>>(
      Qb, Kb, nullptr, Sc, 0.03125f,
      (long long)S_ * D_, (long long)S_ * D_, (long long)S_ * S_);

  k_softmax_colsum<<<dim3(S_ / 32, B_), 256, 0, stream>>>(Sc, pmask, c);
  k_cv<<<dim3(S_ / 64, B_), 256, 0, stream>>>(c, Vb, pooled);
  k_mlp1<<<dim3(16, 4), 256, 0, stream>>>(pooled, W1, hpre);
  k_mlp2<<<dim3(4, 16), 256, 0, stream>>>(hpre, b1, W2, outpre);
  k_finish<<<64, 256, 0, stream>>>(outpre, b2, out);
}